// Round 1
// baseline (1361.989 us; speedup 1.0000x reference)
//
#include <hip/hip_runtime.h>
#include <hip/hip_bf16.h>

typedef __hip_bfloat16 bf16;

constexpr int B = 16, CIN = 3, H = 256, W = 256;
constexpr int OPL = 32, WAVC = 12, OC = 96;
#define EPS 1e-5f

// ---------------- avg pool 2x2 ----------------
__global__ void k_avgpool(const float* __restrict__ in, float* __restrict__ out,
                          int Ho, int Wo) {
  int n = B * CIN * Ho * Wo;
  int i = blockIdx.x * blockDim.x + threadIdx.x;
  if (i >= n) return;
  int x = i % Wo, y = (i / Wo) % Ho, p = i / (Wo * Ho);
  int Wi = Wo * 2;
  const float* ip = in + (size_t)p * (Ho * 2) * Wi + (size_t)(2 * y) * Wi + 2 * x;
  out[i] = 0.25f * (ip[0] + ip[1] + ip[Wi] + ip[Wi + 1]);
}

// ---------------- Haar bands (half res) ----------------
__global__ void k_bands(const float* __restrict__ cur, float* __restrict__ bands,
                        int Hl, int Wl) {
  int h2 = Hl >> 1, w2 = Wl >> 1;
  int n = B * CIN * h2 * w2;
  int i = blockIdx.x * blockDim.x + threadIdx.x;
  if (i >= n) return;
  int x = i % w2, y = (i / w2) % h2, c = (i / (w2 * h2)) % CIN, b = i / (w2 * h2 * CIN);
  const float* ip = cur + (size_t)(b * CIN + c) * Hl * Wl + (size_t)(2 * y) * Wl + 2 * x;
  float e = ip[0], f = ip[1], g = ip[Wl], h = ip[Wl + 1];
  size_t plane = (size_t)h2 * w2;
  float* op = bands + (size_t)(b * WAVC + c * 4) * plane + (size_t)y * w2 + x;
  op[0]         = (e + f + g + h) * 0.5f;
  op[plane]     = (e + f - g - h) * 0.5f;
  op[2 * plane] = (e - f + g - h) * 0.5f;
  op[3 * plane] = (e - f - g + h) * 0.5f;
}

// jax.image.resize bilinear: s=(o+0.5)/r-0.5, edge renormalize == clamp
__device__ inline void bil_coord(int o, int r, int n, int& i0, int& i1, float& w1) {
  float s = (o + 0.5f) / (float)r - 0.5f;
  float fl = floorf(s);
  w1 = s - fl;
  int y0 = (int)fl;
  i0 = y0 < 0 ? 0 : y0;
  i1 = (y0 + 1 > n - 1) ? (n - 1) : (y0 + 1);
}

// ---------------- bilinear x2 upsample f32 -> bf16 ----------------
__global__ void k_upsample_b(const float* __restrict__ in, bf16* __restrict__ out,
                             int C, int hi, int wi) {
  int ho = hi * 2, wo = wi * 2;
  int n = B * C * ho * wo;
  int i = blockIdx.x * blockDim.x + threadIdx.x;
  if (i >= n) return;
  int x = i % wo, y = (i / wo) % ho, p = i / (wo * ho);
  int x0, x1, y0, y1; float wx, wy;
  bil_coord(x, 2, wi, x0, x1, wx);
  bil_coord(y, 2, hi, y0, y1, wy);
  const float* ip = in + (size_t)p * hi * wi;
  float v00 = ip[(size_t)y0 * wi + x0], v01 = ip[(size_t)y0 * wi + x1];
  float v10 = ip[(size_t)y1 * wi + x0], v11 = ip[(size_t)y1 * wi + x1];
  float v = (1.f - wy) * ((1.f - wx) * v00 + wx * v01)
          + wy * ((1.f - wx) * v10 + wx * v11);
  out[i] = __float2bfloat16(v);
}

// ---------------- conv3x3 SAME, 12 -> 32 ch ----------------
// block: 256 threads = 16x16; each thread computes 2 pixels (y, y+16) x 32 oc.
__global__ void __launch_bounds__(256) k_conv3(const bf16* __restrict__ wav,
    const float* __restrict__ wt, const float* __restrict__ bias,
    float* __restrict__ fraw, int Hl, int Wl) {
  __shared__ float sIn[WAVC][34][18];
  __shared__ float sW[WAVC * 9][OPL];   // transposed: [ic*9+k][oc] -> b128 reads
  int b = blockIdx.z;
  int ty0 = blockIdx.y * 32, tx0 = blockIdx.x * 16;
  int tid = threadIdx.x;
  for (int idx = tid; idx < WAVC * 9 * OPL; idx += 256) {
    int oc = idx & 31, k9 = idx >> 5;
    sW[k9][oc] = wt[oc * (WAVC * 9) + k9];
  }
  size_t plane = (size_t)Hl * Wl;
  const bf16* ip = wav + (size_t)b * WAVC * plane;
  for (int idx = tid; idx < WAVC * 34 * 18; idx += 256) {
    int lx = idx % 18, ly = (idx / 18) % 34, ic = idx / (18 * 34);
    int gy = ty0 + ly - 1, gx = tx0 + lx - 1;
    float v = 0.f;
    if (gy >= 0 && gy < Hl && gx >= 0 && gx < Wl)
      v = __bfloat162float(ip[ic * plane + (size_t)gy * Wl + gx]);
    sIn[ic][ly][lx] = v;
  }
  __syncthreads();
  int lx = tid & 15, ly = tid >> 4;
  float acc0[OPL], acc1[OPL];
#pragma unroll
  for (int o = 0; o < OPL; o++) { acc0[o] = 0.f; acc1[o] = 0.f; }
  for (int ic = 0; ic < WAVC; ic++) {
#pragma unroll
    for (int ky = 0; ky < 3; ky++) {
#pragma unroll
      for (int kx = 0; kx < 3; kx++) {
        float v0 = sIn[ic][ly + ky][lx + kx];
        float v1 = sIn[ic][ly + 16 + ky][lx + kx];
        const float* wp = sW[ic * 9 + ky * 3 + kx];
#pragma unroll
        for (int o = 0; o < OPL; o++) {
          acc0[o] = fmaf(v0, wp[o], acc0[o]);
          acc1[o] = fmaf(v1, wp[o], acc1[o]);
        }
      }
    }
  }
  int x = tx0 + lx, ya = ty0 + ly, yb = ya + 16;
  float* opa = fraw + (size_t)b * OPL * plane + (size_t)ya * Wl + x;
  float* opb = fraw + (size_t)b * OPL * plane + (size_t)yb * Wl + x;
  for (int o = 0; o < OPL; o++) {
    float bb = bias[o];
    opa[o * plane] = acc0[o] + bb;
    opb[o * plane] = acc1[o] + bb;
  }
}

// ---------------- per-(b,c)-plane mean / rstd; one block per plane ----------------
__global__ void k_stats(const float* __restrict__ xin, float* __restrict__ stats,
                        int plane, float invN) {
  int p = blockIdx.x;
  const float* xp = xin + (size_t)p * plane;
  float s = 0.f, s2 = 0.f;
  for (int i = threadIdx.x; i < plane; i += blockDim.x) {
    float v = xp[i];
    s += v; s2 += v * v;
  }
  __shared__ float rs[4], rs2[4];
  for (int off = 32; off > 0; off >>= 1) {
    s += __shfl_down(s, off);
    s2 += __shfl_down(s2, off);
  }
  int lane = threadIdx.x & 63, wid = threadIdx.x >> 6;
  if (lane == 0) { rs[wid] = s; rs2[wid] = s2; }
  __syncthreads();
  if (threadIdx.x == 0) {
    float S = rs[0] + rs[1] + rs[2] + rs[3];
    float S2 = rs2[0] + rs2[1] + rs2[2] + rs2[3];
    float mean = S * invN;
    float var = S2 * invN - mean * mean;
    stats[2 * p] = mean;
    stats[2 * p + 1] = rsqrtf(var + EPS);
  }
}

// ---------------- level 0: normalize + prelu -> cat channels [0,32) ----------------
__global__ void k_norm0(const float* __restrict__ fraw, const float* __restrict__ stats,
                        const float* __restrict__ a, bf16* __restrict__ cat) {
  int i = blockIdx.x * blockDim.x + threadIdx.x;
  if (i >= B * OPL * H * W) return;
  int pc = i >> 16;               // b*32 + c
  int b = pc >> 5, c = pc & 31;
  float mean = stats[2 * pc], rstd = stats[2 * pc + 1];
  float v = (fraw[i] - mean) * rstd;
  float al = a[0];
  v = v >= 0.f ? v : al * v;
  cat[(((size_t)(b * OC + c)) << 16) + (i & 65535)] = __float2bfloat16(v);
}

// ---------------- levels 1/2: normalize + prelu + bilinear up to 256^2 ----------------
// prelu applied BEFORE interpolation (matches resize(prelu(IN(.))))
__global__ void k_upnorm(const float* __restrict__ fraw, const float* __restrict__ stats,
                         const float* __restrict__ a, bf16* __restrict__ cat,
                         int Hl, int r, int cofs) {
  int i = blockIdx.x * blockDim.x + threadIdx.x;
  if (i >= B * OPL * H * W) return;
  int x = i & 255, y = (i >> 8) & 255;
  int pc = i >> 16;               // b*32 + c
  int b = pc >> 5, c = pc & 31;
  float mean = stats[2 * pc], rstd = stats[2 * pc + 1];
  float al = a[0];
  int x0, x1, y0, y1; float wx, wy;
  bil_coord(x, r, Hl, x0, x1, wx);
  bil_coord(y, r, Hl, y0, y1, wy);
  const float* ip = fraw + (size_t)pc * Hl * Hl;
  float v00 = ip[(size_t)y0 * Hl + x0], v01 = ip[(size_t)y0 * Hl + x1];
  float v10 = ip[(size_t)y1 * Hl + x0], v11 = ip[(size_t)y1 * Hl + x1];
  v00 = (v00 - mean) * rstd; v00 = v00 >= 0.f ? v00 : al * v00;
  v01 = (v01 - mean) * rstd; v01 = v01 >= 0.f ? v01 : al * v01;
  v10 = (v10 - mean) * rstd; v10 = v10 >= 0.f ? v10 : al * v10;
  v11 = (v11 - mean) * rstd; v11 = v11 >= 0.f ? v11 : al * v11;
  float v = (1.f - wy) * ((1.f - wx) * v00 + wx * v01)
          + wy * ((1.f - wx) * v10 + wx * v11);
  cat[(((size_t)(b * OC + cofs + c)) << 16) + (y << 8) + x] = __float2bfloat16(v);
}

// ---------------- final 1x1 conv, 96 -> 96 (raw, pre-IN) into d_out ----------------
// each thread: 2 pixels x 96 oc; weights transposed in LDS ([ic][oc] -> ds_read_b128)
__global__ void __launch_bounds__(256) k_conv1x1(const bf16* __restrict__ cat,
    const float* __restrict__ wf, const float* __restrict__ bfv,
    float* __restrict__ out) {
  __shared__ float sW[OC][OC];   // [ic][oc]
  int tid = threadIdx.x;
  for (int idx = tid; idx < OC * OC; idx += 256) {
    int oc = idx % OC, ic = idx / OC;
    sW[ic][oc] = wf[oc * OC + ic];
  }
  __syncthreads();
  int b = blockIdx.x >> 7;                 // 128 blocks per image
  int pix = (blockIdx.x & 127) * 512 + tid;
  const bf16* ip = cat + ((size_t)(b * OC) << 16) + pix;
  float accx[OC], accy[OC];
#pragma unroll
  for (int o = 0; o < OC; o++) { accx[o] = 0.f; accy[o] = 0.f; }
  for (int ic = 0; ic < OC; ic++) {
    float xa = __bfloat162float(ip[(size_t)ic << 16]);
    float xb = __bfloat162float(ip[((size_t)ic << 16) + 256]);
    const float* wp = sW[ic];
#pragma unroll
    for (int o = 0; o < OC; o++) {
      accx[o] = fmaf(xa, wp[o], accx[o]);
      accy[o] = fmaf(xb, wp[o], accy[o]);
    }
  }
  float* op = out + ((size_t)(b * OC) << 16) + pix;
  for (int o = 0; o < OC; o++) {
    float bb = bfv[o];
    op[(size_t)o << 16] = accx[o] + bb;
    op[((size_t)o << 16) + 256] = accy[o] + bb;
  }
}

// ---------------- final IN + prelu, in place on d_out ----------------
__global__ void k_normF(float* __restrict__ out, const float* __restrict__ stats,
                        const float* __restrict__ a) {
  int i = blockIdx.x * blockDim.x + threadIdx.x;
  if (i >= B * OC * H * W) return;
  int p = i >> 16;
  float mean = stats[2 * p], rstd = stats[2 * p + 1];
  float v = (out[i] - mean) * rstd;
  float al = a[0];
  out[i] = v >= 0.f ? v : al * v;
}

extern "C" void kernel_launch(void* const* d_in, const int* in_sizes, int n_in,
                              void* d_out, int out_size, void* d_ws, size_t ws_size,
                              hipStream_t stream) {
  const float* x   = (const float*)d_in[0];
  const float* w[3]  = {(const float*)d_in[1], (const float*)d_in[4], (const float*)d_in[7]};
  const float* bb[3] = {(const float*)d_in[2], (const float*)d_in[5], (const float*)d_in[8]};
  const float* aa[3] = {(const float*)d_in[3], (const float*)d_in[6], (const float*)d_in[9]};
  const float* wf  = (const float*)d_in[10];
  const float* bfv = (const float*)d_in[11];
  const float* af  = (const float*)d_in[12];
  float* out = (float*)d_out;

  // workspace layout (bytes):
  //   cat  bf16  16*96*65536*2 = 201,326,592
  //   wav  bf16  16*12*65536*2 =  25,165,824
  //   fraw f32   16*32*65536*4 = 134,217,728  (bands aliases its head)
  //   cur1 f32   786,432 el; cur2 f32 196,608 el; stats f32 3,072 el
  char* ws = (char*)d_ws;
  bf16*  cat  = (bf16*)ws;
  bf16*  wav  = (bf16*)(ws + 201326592ull);
  float* fraw = (float*)(ws + 201326592ull + 25165824ull);
  float* bands = fraw;                       // alias: dead before fraw is written
  float* cur1 = (float*)(ws + 201326592ull + 25165824ull + 134217728ull);
  float* cur2 = cur1 + 786432;
  float* stats = cur2 + 196608;

  auto cdiv = [](int a, int b) { return (a + b - 1) / b; };

  k_avgpool<<<cdiv(B * CIN * 128 * 128, 256), 256, 0, stream>>>(x, cur1, 128, 128);
  k_avgpool<<<cdiv(B * CIN * 64 * 64, 256), 256, 0, stream>>>(cur1, cur2, 64, 64);

  const float* curp[3] = {x, cur1, cur2};
  int Hls[3] = {256, 128, 64};
  for (int l = 0; l < 3; l++) {
    int Hl = Hls[l], h2 = Hl / 2;
    k_bands<<<cdiv(B * CIN * h2 * h2, 256), 256, 0, stream>>>(curp[l], bands, Hl, Hl);
    k_upsample_b<<<cdiv(B * WAVC * Hl * Hl, 256), 256, 0, stream>>>(bands, wav, WAVC, h2, h2);
    dim3 g3(Hl / 16, Hl / 32, B);
    k_conv3<<<g3, 256, 0, stream>>>(wav, w[l], bb[l], fraw, Hl, Hl);
    k_stats<<<B * OPL, 256, 0, stream>>>(fraw, stats, Hl * Hl, 1.f / (float)(Hl * Hl));
    if (l == 0)
      k_norm0<<<cdiv(B * OPL * H * W, 256), 256, 0, stream>>>(fraw, stats, aa[0], cat);
    else
      k_upnorm<<<cdiv(B * OPL * H * W, 256), 256, 0, stream>>>(fraw, stats, aa[l], cat,
                                                               Hl, 256 / Hl, l * OPL);
  }
  k_conv1x1<<<B * 128, 256, 0, stream>>>(cat, wf, bfv, out);
  k_stats<<<B * OC, 256, 0, stream>>>(out, stats, H * W, 1.f / (float)(H * W));
  k_normF<<<cdiv(B * OC * H * W, 256), 256, 0, stream>>>(out, stats, af);
}

// Round 2
// 912.475 us; speedup vs baseline: 1.4926x; 1.4926x over previous
//
#include <hip/hip_runtime.h>
#include <hip/hip_bf16.h>

typedef __hip_bfloat16 bf16;
typedef __attribute__((ext_vector_type(8))) short bf16x8;
typedef __attribute__((ext_vector_type(4))) float f32x4;

constexpr int B = 16, CIN = 3, H = 256, W = 256;
constexpr int OPL = 32, WAVC = 12, OC = 96;
#define EPS 1e-5f

// ---------------- avg pool 2x2 ----------------
__global__ void k_avgpool(const float* __restrict__ in, float* __restrict__ out,
                          int Ho, int Wo) {
  int n = B * CIN * Ho * Wo;
  int i = blockIdx.x * blockDim.x + threadIdx.x;
  if (i >= n) return;
  int x = i % Wo, y = (i / Wo) % Ho, p = i / (Wo * Ho);
  int Wi = Wo * 2;
  const float* ip = in + (size_t)p * (Ho * 2) * Wi + (size_t)(2 * y) * Wi + 2 * x;
  out[i] = 0.25f * (ip[0] + ip[1] + ip[Wi] + ip[Wi + 1]);
}

// ---------------- Haar bands (half res) ----------------
__global__ void k_bands(const float* __restrict__ cur, float* __restrict__ bands,
                        int Hl, int Wl) {
  int h2 = Hl >> 1, w2 = Wl >> 1;
  int n = B * CIN * h2 * w2;
  int i = blockIdx.x * blockDim.x + threadIdx.x;
  if (i >= n) return;
  int x = i % w2, y = (i / w2) % h2, c = (i / (w2 * h2)) % CIN, b = i / (w2 * h2 * CIN);
  const float* ip = cur + (size_t)(b * CIN + c) * Hl * Wl + (size_t)(2 * y) * Wl + 2 * x;
  float e = ip[0], f = ip[1], g = ip[Wl], h = ip[Wl + 1];
  size_t plane = (size_t)h2 * w2;
  float* op = bands + (size_t)(b * WAVC + c * 4) * plane + (size_t)y * w2 + x;
  op[0]         = (e + f + g + h) * 0.5f;
  op[plane]     = (e + f - g - h) * 0.5f;
  op[2 * plane] = (e - f + g - h) * 0.5f;
  op[3 * plane] = (e - f - g + h) * 0.5f;
}

// jax.image.resize bilinear: s=(o+0.5)/r-0.5, edge renormalize == clamp
__device__ inline void bil_coord(int o, int r, int n, int& i0, int& i1, float& w1) {
  float s = (o + 0.5f) / (float)r - 0.5f;
  float fl = floorf(s);
  w1 = s - fl;
  int y0 = (int)fl;
  i0 = y0 < 0 ? 0 : y0;
  i1 = (y0 + 1 > n - 1) ? (n - 1) : (y0 + 1);
}

// ---------------- bilinear x2 upsample f32 -> bf16 ----------------
__global__ void k_upsample_b(const float* __restrict__ in, bf16* __restrict__ out,
                             int C, int hi, int wi) {
  int ho = hi * 2, wo = wi * 2;
  int n = B * C * ho * wo;
  int i = blockIdx.x * blockDim.x + threadIdx.x;
  if (i >= n) return;
  int x = i % wo, y = (i / wo) % ho, p = i / (wo * ho);
  int x0, x1, y0, y1; float wx, wy;
  bil_coord(x, 2, wi, x0, x1, wx);
  bil_coord(y, 2, hi, y0, y1, wy);
  const float* ip = in + (size_t)p * hi * wi;
  float v00 = ip[(size_t)y0 * wi + x0], v01 = ip[(size_t)y0 * wi + x1];
  float v10 = ip[(size_t)y1 * wi + x0], v11 = ip[(size_t)y1 * wi + x1];
  float v = (1.f - wy) * ((1.f - wx) * v00 + wx * v01)
          + wy * ((1.f - wx) * v10 + wx * v11);
  out[i] = __float2bfloat16(v);
}

// ---------------- conv3x3 SAME, 12 -> 32 ch ----------------
__global__ void __launch_bounds__(256) k_conv3(const bf16* __restrict__ wav,
    const float* __restrict__ wt, const float* __restrict__ bias,
    float* __restrict__ fraw, int Hl, int Wl) {
  __shared__ float sIn[WAVC][34][18];
  __shared__ float sW[WAVC * 9][OPL];
  int b = blockIdx.z;
  int ty0 = blockIdx.y * 32, tx0 = blockIdx.x * 16;
  int tid = threadIdx.x;
  for (int idx = tid; idx < WAVC * 9 * OPL; idx += 256) {
    int oc = idx & 31, k9 = idx >> 5;
    sW[k9][oc] = wt[oc * (WAVC * 9) + k9];
  }
  size_t plane = (size_t)Hl * Wl;
  const bf16* ip = wav + (size_t)b * WAVC * plane;
  for (int idx = tid; idx < WAVC * 34 * 18; idx += 256) {
    int lx = idx % 18, ly = (idx / 18) % 34, ic = idx / (18 * 34);
    int gy = ty0 + ly - 1, gx = tx0 + lx - 1;
    float v = 0.f;
    if (gy >= 0 && gy < Hl && gx >= 0 && gx < Wl)
      v = __bfloat162float(ip[ic * plane + (size_t)gy * Wl + gx]);
    sIn[ic][ly][lx] = v;
  }
  __syncthreads();
  int lx = tid & 15, ly = tid >> 4;
  float acc0[OPL], acc1[OPL];
#pragma unroll
  for (int o = 0; o < OPL; o++) { acc0[o] = 0.f; acc1[o] = 0.f; }
  for (int ic = 0; ic < WAVC; ic++) {
#pragma unroll
    for (int ky = 0; ky < 3; ky++) {
#pragma unroll
      for (int kx = 0; kx < 3; kx++) {
        float v0 = sIn[ic][ly + ky][lx + kx];
        float v1 = sIn[ic][ly + 16 + ky][lx + kx];
        const float* wp = sW[ic * 9 + ky * 3 + kx];
#pragma unroll
        for (int o = 0; o < OPL; o++) {
          acc0[o] = fmaf(v0, wp[o], acc0[o]);
          acc1[o] = fmaf(v1, wp[o], acc1[o]);
        }
      }
    }
  }
  int x = tx0 + lx, ya = ty0 + ly, yb = ya + 16;
  float* opa = fraw + (size_t)b * OPL * plane + (size_t)ya * Wl + x;
  float* opb = fraw + (size_t)b * OPL * plane + (size_t)yb * Wl + x;
  for (int o = 0; o < OPL; o++) {
    float bb = bias[o];
    opa[o * plane] = acc0[o] + bb;
    opb[o * plane] = acc1[o] + bb;
  }
}

// ---------------- per-(b,c)-plane mean / rstd ----------------
__global__ void k_stats(const float* __restrict__ xin, float* __restrict__ stats,
                        int plane, float invN) {
  int p = blockIdx.x;
  const float* xp = xin + (size_t)p * plane;
  float s = 0.f, s2 = 0.f;
  for (int i = threadIdx.x; i < plane; i += blockDim.x) {
    float v = xp[i];
    s += v; s2 += v * v;
  }
  __shared__ float rs[4], rs2[4];
  for (int off = 32; off > 0; off >>= 1) {
    s += __shfl_down(s, off);
    s2 += __shfl_down(s2, off);
  }
  int lane = threadIdx.x & 63, wid = threadIdx.x >> 6;
  if (lane == 0) { rs[wid] = s; rs2[wid] = s2; }
  __syncthreads();
  if (threadIdx.x == 0) {
    float S = rs[0] + rs[1] + rs[2] + rs[3];
    float S2 = rs2[0] + rs2[1] + rs2[2] + rs2[3];
    float mean = S * invN;
    float var = S2 * invN - mean * mean;
    stats[2 * p] = mean;
    stats[2 * p + 1] = rsqrtf(var + EPS);
  }
}

// ---------------- level 0: normalize + prelu -> cat channels [0,32) ----------------
__global__ void k_norm0(const float* __restrict__ fraw, const float* __restrict__ stats,
                        const float* __restrict__ a, bf16* __restrict__ cat) {
  int i = blockIdx.x * blockDim.x + threadIdx.x;
  if (i >= B * OPL * H * W) return;
  int pc = i >> 16;
  int b = pc >> 5, c = pc & 31;
  float mean = stats[2 * pc], rstd = stats[2 * pc + 1];
  float v = (fraw[i] - mean) * rstd;
  float al = a[0];
  v = v >= 0.f ? v : al * v;
  cat[(((size_t)(b * OC + c)) << 16) + (i & 65535)] = __float2bfloat16(v);
}

// ---------------- levels 1/2: normalize + prelu + bilinear up ----------------
__global__ void k_upnorm(const float* __restrict__ fraw, const float* __restrict__ stats,
                         const float* __restrict__ a, bf16* __restrict__ cat,
                         int Hl, int r, int cofs) {
  int i = blockIdx.x * blockDim.x + threadIdx.x;
  if (i >= B * OPL * H * W) return;
  int x = i & 255, y = (i >> 8) & 255;
  int pc = i >> 16;
  int b = pc >> 5, c = pc & 31;
  float mean = stats[2 * pc], rstd = stats[2 * pc + 1];
  float al = a[0];
  int x0, x1, y0, y1; float wx, wy;
  bil_coord(x, r, Hl, x0, x1, wx);
  bil_coord(y, r, Hl, y0, y1, wy);
  const float* ip = fraw + (size_t)pc * Hl * Hl;
  float v00 = ip[(size_t)y0 * Hl + x0], v01 = ip[(size_t)y0 * Hl + x1];
  float v10 = ip[(size_t)y1 * Hl + x0], v11 = ip[(size_t)y1 * Hl + x1];
  v00 = (v00 - mean) * rstd; v00 = v00 >= 0.f ? v00 : al * v00;
  v01 = (v01 - mean) * rstd; v01 = v01 >= 0.f ? v01 : al * v01;
  v10 = (v10 - mean) * rstd; v10 = v10 >= 0.f ? v10 : al * v10;
  v11 = (v11 - mean) * rstd; v11 = v11 >= 0.f ? v11 : al * v11;
  float v = (1.f - wy) * ((1.f - wx) * v00 + wx * v01)
          + wy * ((1.f - wx) * v10 + wx * v11);
  cat[(((size_t)(b * OC + cofs + c)) << 16) + (y << 8) + x] = __float2bfloat16(v);
}

// ---------------- weights fp32 -> bf16 ----------------
__global__ void k_wprep(const float* __restrict__ wf, bf16* __restrict__ wbf) {
  int i = blockIdx.x * 256 + threadIdx.x;
  if (i < OC * OC) wbf[i] = __float2bfloat16(wf[i]);
}

// ---------------- second moments of cat per batch: G2 = cat*cat^T, musum ----------------
// grid: 16 b x 32 chunks (2048 px); 384 threads = 6 waves (wave = row tile)
__global__ void __launch_bounds__(384) k_moments(const bf16* __restrict__ cat,
    float* __restrict__ G2, float* __restrict__ musum) {
  int b = blockIdx.x >> 5;
  int chunk = blockIdx.x & 31;
  int ti = threadIdx.x >> 6;
  int l = threadIdx.x & 63;
  int lr = l & 15, kg = l >> 4;
  const bf16* base = cat + ((size_t)(b * OC) << 16);
  f32x4 acc0 = {0,0,0,0}, acc1 = {0,0,0,0}, acc2 = {0,0,0,0};
  f32x4 acc3 = {0,0,0,0}, acc4 = {0,0,0,0}, acc5 = {0,0,0,0};
  f32x4 accO = {0,0,0,0};
  bf16x8 ones;
#pragma unroll
  for (int j = 0; j < 8; j++) ones[j] = (short)0x3F80;  // bf16 1.0
  int p0 = chunk * 2048 + kg * 8;
  const bf16* arow = base + (((size_t)(ti * 16 + lr)) << 16);
#pragma unroll 2
  for (int s = 0; s < 64; s++) {
    int p = p0 + s * 32;
    bf16x8 fa = *(const bf16x8*)(arow + p);
    bf16x8 f0 = *(const bf16x8*)(base + (((size_t)(0 + lr)) << 16) + p);
    bf16x8 f1 = *(const bf16x8*)(base + (((size_t)(16 + lr)) << 16) + p);
    bf16x8 f2 = *(const bf16x8*)(base + (((size_t)(32 + lr)) << 16) + p);
    bf16x8 f3 = *(const bf16x8*)(base + (((size_t)(48 + lr)) << 16) + p);
    bf16x8 f4 = *(const bf16x8*)(base + (((size_t)(64 + lr)) << 16) + p);
    bf16x8 f5 = *(const bf16x8*)(base + (((size_t)(80 + lr)) << 16) + p);
    acc0 = __builtin_amdgcn_mfma_f32_16x16x32_bf16(fa, f0, acc0, 0, 0, 0);
    acc1 = __builtin_amdgcn_mfma_f32_16x16x32_bf16(fa, f1, acc1, 0, 0, 0);
    acc2 = __builtin_amdgcn_mfma_f32_16x16x32_bf16(fa, f2, acc2, 0, 0, 0);
    acc3 = __builtin_amdgcn_mfma_f32_16x16x32_bf16(fa, f3, acc3, 0, 0, 0);
    acc4 = __builtin_amdgcn_mfma_f32_16x16x32_bf16(fa, f4, acc4, 0, 0, 0);
    acc5 = __builtin_amdgcn_mfma_f32_16x16x32_bf16(fa, f5, acc5, 0, 0, 0);
    accO = __builtin_amdgcn_mfma_f32_16x16x32_bf16(fa, ones, accO, 0, 0, 0);
  }
  f32x4 accs[6] = {acc0, acc1, acc2, acc3, acc4, acc5};
#pragma unroll
  for (int t = 0; t < 6; t++)
#pragma unroll
    for (int r = 0; r < 4; r++) {
      int i = ti * 16 + kg * 4 + r, j = t * 16 + lr;
      atomicAdd(&G2[(size_t)(b * OC + i) * OC + j], accs[t][r]);
    }
#pragma unroll
  for (int r = 0; r < 4; r++) {
    int i = ti * 16 + kg * 4 + r;
    if (lr == 0) atomicAdd(&musum[b * OC + i], accO[r]);
  }
}

// ---------------- combine: per (b,oc) scale/shift for fused IN ----------------
__global__ void __launch_bounds__(128) k_statsF(const float* __restrict__ G2,
    const float* __restrict__ musum, const float* __restrict__ wf,
    const float* __restrict__ bfv, float* __restrict__ scale,
    float* __restrict__ shift) {
  int oc = blockIdx.x, b = blockIdx.y;
  int j = threadIdx.x;
  float quad = 0.f, lin = 0.f;
  if (j < OC) {
    float wj = __bfloat162float(__float2bfloat16(wf[oc * OC + j]));
    const float* g = G2 + (size_t)(b * OC) * OC + j;
    float inner = 0.f;
#pragma unroll 4
    for (int i = 0; i < OC; i++) {
      float wi = __bfloat162float(__float2bfloat16(wf[oc * OC + i]));
      inner = fmaf(wi, g[(size_t)i * OC], inner);
    }
    quad = wj * inner;
    lin = wj * musum[b * OC + j];
  }
  __shared__ float rq[2], rl[2];
  for (int off = 32; off > 0; off >>= 1) {
    quad += __shfl_down(quad, off);
    lin += __shfl_down(lin, off);
  }
  if ((threadIdx.x & 63) == 0) { rq[threadIdx.x >> 6] = quad; rl[threadIdx.x >> 6] = lin; }
  __syncthreads();
  if (threadIdx.x == 0) {
    float Q = rq[0] + rq[1], L = rl[0] + rl[1];
    const float invN = 1.f / 65536.f;
    float bias = bfv[oc];
    float mean = L * invN + bias;
    float e2 = Q * invN + 2.f * bias * (L * invN) + bias * bias;
    float var = e2 - mean * mean;
    float rstd = rsqrtf(fmaxf(var, 0.f) + EPS);
    scale[b * OC + oc] = rstd;
    shift[b * OC + oc] = (bias - mean) * rstd;
  }
}

// ---------------- fused final conv1x1 (MFMA) + IN + prelu -> d_out ----------------
// block = 256 thr (4 waves), covers 1024 px; 8 rounds of 128 px staged in LDS
constexpr int CROW = 52;  // dwords per px row (96 bf16 = 48 dw + 4 pad)
__global__ void __launch_bounds__(256) k_conv1x1f(const bf16* __restrict__ cat,
    const bf16* __restrict__ wbf, const float* __restrict__ scale,
    const float* __restrict__ shift, const float* __restrict__ af,
    float* __restrict__ out) {
  __shared__ unsigned int sT[128 * CROW];
  int b = blockIdx.x >> 6;
  int px0 = (blockIdx.x & 63) * 1024;
  int tid = threadIdx.x, w = tid >> 6, l = tid & 63;
  int lr = l & 15, kg = l >> 4;
  // weight fragments: A operand, free=oc(lane&15), k=ic
  bf16x8 wf_[6][3];
#pragma unroll
  for (int t = 0; t < 6; t++)
#pragma unroll
    for (int ks = 0; ks < 3; ks++)
      wf_[t][ks] = *(const bf16x8*)(wbf + (t * 16 + lr) * OC + ks * 32 + kg * 8);
  float al = af[0];
  int bo = b * OC;
  float sc[6][4], sh[6][4];
#pragma unroll
  for (int t = 0; t < 6; t++)
#pragma unroll
    for (int r = 0; r < 4; r++) {
      int oc = t * 16 + kg * 4 + r;
      sc[t][r] = scale[bo + oc];
      sh[t][r] = shift[bo + oc];
    }
  const bf16* cb = cat + ((size_t)bo << 16);
  for (int round = 0; round < 8; round++) {
    int rp0 = px0 + round * 128;
    __syncthreads();
    // stage 128 px x 96 ic, transposed + ic-pair packed
#pragma unroll
    for (int k = 0; k < 3; k++) {
      int it = tid + k * 256;
      int p = it % 48, g = it / 48;
      const bf16* r0 = cb + (((size_t)(2 * p)) << 16) + rp0 + g * 8;
      bf16x8 a = *(const bf16x8*)r0;
      bf16x8 c = *(const bf16x8*)(r0 + 65536);
#pragma unroll
      for (int j = 0; j < 8; j++) {
        unsigned int d = (unsigned int)(unsigned short)a[j]
                       | ((unsigned int)(unsigned short)c[j] << 16);
        sT[(g * 8 + j) * CROW + p] = d;
      }
    }
    __syncthreads();
#pragma unroll
    for (int pt = 0; pt < 2; pt++) {
      int tloc = w * 2 + pt;
      int pl = tloc * 16 + lr;
      f32x4 a0 = {0,0,0,0}, a1 = {0,0,0,0}, a2 = {0,0,0,0};
      f32x4 a3 = {0,0,0,0}, a4 = {0,0,0,0}, a5 = {0,0,0,0};
#pragma unroll
      for (int ks = 0; ks < 3; ks++) {
        bf16x8 bf_ = *(const bf16x8*)&sT[pl * CROW + ks * 16 + kg * 4];
        a0 = __builtin_amdgcn_mfma_f32_16x16x32_bf16(wf_[0][ks], bf_, a0, 0, 0, 0);
        a1 = __builtin_amdgcn_mfma_f32_16x16x32_bf16(wf_[1][ks], bf_, a1, 0, 0, 0);
        a2 = __builtin_amdgcn_mfma_f32_16x16x32_bf16(wf_[2][ks], bf_, a2, 0, 0, 0);
        a3 = __builtin_amdgcn_mfma_f32_16x16x32_bf16(wf_[3][ks], bf_, a3, 0, 0, 0);
        a4 = __builtin_amdgcn_mfma_f32_16x16x32_bf16(wf_[4][ks], bf_, a4, 0, 0, 0);
        a5 = __builtin_amdgcn_mfma_f32_16x16x32_bf16(wf_[5][ks], bf_, a5, 0, 0, 0);
      }
      f32x4 accs[6] = {a0, a1, a2, a3, a4, a5};
      int px = rp0 + tloc * 16 + lr;
#pragma unroll
      for (int t = 0; t < 6; t++)
#pragma unroll
        for (int r = 0; r < 4; r++) {
          int oc = t * 16 + kg * 4 + r;
          float v = accs[t][r] * sc[t][r] + sh[t][r];
          v = v >= 0.f ? v : al * v;
          out[((size_t)(bo + oc) << 16) + px] = v;
        }
    }
  }
}

extern "C" void kernel_launch(void* const* d_in, const int* in_sizes, int n_in,
                              void* d_out, int out_size, void* d_ws, size_t ws_size,
                              hipStream_t stream) {
  const float* x   = (const float*)d_in[0];
  const float* w[3]  = {(const float*)d_in[1], (const float*)d_in[4], (const float*)d_in[7]};
  const float* bb[3] = {(const float*)d_in[2], (const float*)d_in[5], (const float*)d_in[8]};
  const float* aa[3] = {(const float*)d_in[3], (const float*)d_in[6], (const float*)d_in[9]};
  const float* wfp = (const float*)d_in[10];
  const float* bfv = (const float*)d_in[11];
  const float* af  = (const float*)d_in[12];
  float* out = (float*)d_out;

  // workspace layout:
  //   cat  bf16  201,326,592 B
  //   wav  bf16   25,165,824 B
  //   fraw f32   134,217,728 B  (bands aliases head)
  //   cur1 f32   786,432 el  -- dead after level-1 k_bands; tail reused:
  //        G2[16*96*96] + musum[16*96] + scale + shift (f32) + wbf (bf16)
  //   cur2 f32   196,608 el; stats f32 3,072 el
  char* ws = (char*)d_ws;
  bf16*  cat  = (bf16*)ws;
  bf16*  wav  = (bf16*)(ws + 201326592ull);
  float* fraw = (float*)(ws + 201326592ull + 25165824ull);
  float* bands = fraw;
  float* cur1 = (float*)(ws + 201326592ull + 25165824ull + 134217728ull);
  float* cur2 = cur1 + 786432;
  float* stats = cur2 + 196608;
  float* G2    = cur1;                    // alias (cur1 dead by then)
  float* musum = G2 + 16 * OC * OC;
  float* scale = musum + 16 * OC;
  float* shift = scale + 16 * OC;
  bf16*  wbf   = (bf16*)(shift + 16 * OC);

  auto cdiv = [](int a, int b) { return (a + b - 1) / b; };

  k_avgpool<<<cdiv(B * CIN * 128 * 128, 256), 256, 0, stream>>>(x, cur1, 128, 128);
  k_avgpool<<<cdiv(B * CIN * 64 * 64, 256), 256, 0, stream>>>(cur1, cur2, 64, 64);

  const float* curp[3] = {x, cur1, cur2};
  int Hls[3] = {256, 128, 64};
  for (int l = 0; l < 3; l++) {
    int Hl = Hls[l], h2 = Hl / 2;
    k_bands<<<cdiv(B * CIN * h2 * h2, 256), 256, 0, stream>>>(curp[l], bands, Hl, Hl);
    k_upsample_b<<<cdiv(B * WAVC * Hl * Hl, 256), 256, 0, stream>>>(bands, wav, WAVC, h2, h2);
    dim3 g3(Hl / 16, Hl / 32, B);
    k_conv3<<<g3, 256, 0, stream>>>(wav, w[l], bb[l], fraw, Hl, Hl);
    k_stats<<<B * OPL, 256, 0, stream>>>(fraw, stats, Hl * Hl, 1.f / (float)(Hl * Hl));
    if (l == 0)
      k_norm0<<<cdiv(B * OPL * H * W, 256), 256, 0, stream>>>(fraw, stats, aa[0], cat);
    else
      k_upnorm<<<cdiv(B * OPL * H * W, 256), 256, 0, stream>>>(fraw, stats, aa[l], cat,
                                                               Hl, 256 / Hl, l * OPL);
  }

  k_wprep<<<36, 256, 0, stream>>>(wfp, wbf);
  hipMemsetAsync(G2, 0, (size_t)(16 * OC * OC + 16 * OC) * sizeof(float), stream);
  k_moments<<<16 * 32, 384, 0, stream>>>(cat, G2, musum);
  dim3 gs(OC, B);
  k_statsF<<<gs, 128, 0, stream>>>(G2, musum, wfp, bfv, scale, shift);
  k_conv1x1f<<<16 * 64, 256, 0, stream>>>(cat, wbf, scale, shift, af, out);
}

// Round 3
// 827.064 us; speedup vs baseline: 1.6468x; 1.1033x over previous
//
#include <hip/hip_runtime.h>
#include <hip/hip_bf16.h>

typedef __hip_bfloat16 bf16;
typedef __attribute__((ext_vector_type(8))) short bf16x8;
typedef __attribute__((ext_vector_type(4))) float f32x4;

constexpr int B = 16, CIN = 3, H = 256, W = 256;
constexpr int OPL = 32, WAVC = 12, OC = 96;
#define EPS 1e-5f

// ---------------- avg pool 2x2 ----------------
__global__ void k_avgpool(const float* __restrict__ in, float* __restrict__ out,
                          int Ho, int Wo) {
  int n = B * CIN * Ho * Wo;
  int i = blockIdx.x * blockDim.x + threadIdx.x;
  if (i >= n) return;
  int x = i % Wo, y = (i / Wo) % Ho, p = i / (Wo * Ho);
  int Wi = Wo * 2;
  const float* ip = in + (size_t)p * (Ho * 2) * Wi + (size_t)(2 * y) * Wi + 2 * x;
  out[i] = 0.25f * (ip[0] + ip[1] + ip[Wi] + ip[Wi + 1]);
}

// ---------------- Haar bands (half res) ----------------
__global__ void k_bands(const float* __restrict__ cur, float* __restrict__ bands,
                        int Hl, int Wl) {
  int h2 = Hl >> 1, w2 = Wl >> 1;
  int n = B * CIN * h2 * w2;
  int i = blockIdx.x * blockDim.x + threadIdx.x;
  if (i >= n) return;
  int x = i % w2, y = (i / w2) % h2, c = (i / (w2 * h2)) % CIN, b = i / (w2 * h2 * CIN);
  const float* ip = cur + (size_t)(b * CIN + c) * Hl * Wl + (size_t)(2 * y) * Wl + 2 * x;
  float e = ip[0], f = ip[1], g = ip[Wl], h = ip[Wl + 1];
  size_t plane = (size_t)h2 * w2;
  float* op = bands + (size_t)(b * WAVC + c * 4) * plane + (size_t)y * w2 + x;
  op[0]         = (e + f + g + h) * 0.5f;
  op[plane]     = (e + f - g - h) * 0.5f;
  op[2 * plane] = (e - f + g - h) * 0.5f;
  op[3 * plane] = (e - f - g + h) * 0.5f;
}

// jax.image.resize bilinear: s=(o+0.5)/r-0.5, edge renormalize == clamp
__device__ inline void bil_coord(int o, int r, int n, int& i0, int& i1, float& w1) {
  float s = (o + 0.5f) / (float)r - 0.5f;
  float fl = floorf(s);
  w1 = s - fl;
  int y0 = (int)fl;
  i0 = y0 < 0 ? 0 : y0;
  i1 = (y0 + 1 > n - 1) ? (n - 1) : (y0 + 1);
}

// ---------------- bilinear x2 upsample f32 -> bf16 ----------------
__global__ void k_upsample_b(const float* __restrict__ in, bf16* __restrict__ out,
                             int C, int hi, int wi) {
  int ho = hi * 2, wo = wi * 2;
  int n = B * C * ho * wo;
  int i = blockIdx.x * blockDim.x + threadIdx.x;
  if (i >= n) return;
  int x = i % wo, y = (i / wo) % ho, p = i / (wo * ho);
  int x0, x1, y0, y1; float wx, wy;
  bil_coord(x, 2, wi, x0, x1, wx);
  bil_coord(y, 2, hi, y0, y1, wy);
  const float* ip = in + (size_t)p * hi * wi;
  float v00 = ip[(size_t)y0 * wi + x0], v01 = ip[(size_t)y0 * wi + x1];
  float v10 = ip[(size_t)y1 * wi + x0], v11 = ip[(size_t)y1 * wi + x1];
  float v = (1.f - wy) * ((1.f - wx) * v00 + wx * v01)
          + wy * ((1.f - wx) * v10 + wx * v11);
  out[i] = __float2bfloat16(v);
}

// ---------------- conv3x3 weight prep: per level, K-packed A fragments ----------------
// layout: wA[level][((r*2+g)*16 + lr)*32 + kk], kk = kg*8+j -> t=kk>>4, ic=kk&15
__global__ void k_wprep3(const float* __restrict__ w0, const float* __restrict__ w1,
                         const float* __restrict__ w2, bf16* __restrict__ wA) {
  int i = blockIdx.x * 256 + threadIdx.x;
  if (i >= 3 * 5120) return;
  int l = i / 5120, rem = i % 5120;
  int entry = rem >> 5, kk = rem & 31;
  int r = entry >> 5, g = (entry >> 4) & 1, lr = entry & 15;
  int t = kk >> 4, ic = kk & 15;
  int tap = 2 * r + t;
  const float* wl = l == 0 ? w0 : (l == 1 ? w1 : w2);
  float v = 0.f;
  if (tap <= 8 && ic < 12) v = wl[((g * 16 + lr) * 12 + ic) * 9 + tap];
  wA[i] = __float2bfloat16(v);
}

// ---------------- conv3x3 SAME via MFMA (9 taps = 5 K-rounds of 2tap x 16ic) --------
// block: 256 thr (4 waves), 32x32 output tile. LDS: ch-contiguous padded tile.
// Fused per-(b,oc) sum/sumsq atomics -> sacc (replaces k_stats).
__global__ void __launch_bounds__(256) k_conv3m(const bf16* __restrict__ wav,
    const bf16* __restrict__ wA, const float* __restrict__ bias,
    float* __restrict__ fraw, float* __restrict__ sacc, int Hl, int ntx) {
  __shared__ unsigned int sInT[34 * 34 * 12];   // [yy][xx][icd], stride 12 dw
  int tile = blockIdx.x, b = blockIdx.y;
  int by = (tile / ntx) * 32, bx = (tile % ntx) * 32;
  int tid = threadIdx.x;
  size_t plane = (size_t)Hl * Hl;
  const unsigned short* wp = (const unsigned short*)wav + (size_t)b * WAVC * plane;

  // stage: pack ic pairs into dwords, zero halo
  for (int it = tid; it < 34 * 6 * 40; it += 256) {
    int xx = it % 40; if (xx >= 34) continue;
    int rest = it / 40, pr = rest % 6, yy = rest / 6;
    int gy = by + yy - 1, gx = bx + xx - 1;
    unsigned int d = 0;
    if (gy >= 0 && gy < Hl && gx >= 0 && gx < Hl) {
      size_t off = (size_t)gy * Hl + gx;
      unsigned int v0 = wp[(2 * pr) * plane + off];
      unsigned int v1 = wp[(2 * pr + 1) * plane + off];
      d = v0 | (v1 << 16);
    }
    sInT[(yy * 34 + xx) * 12 + pr] = d;
  }
  for (int it = tid; it < 34 * 34; it += 256) {
    sInT[it * 12 + 6] = 0;
    sInT[it * 12 + 7] = 0;
  }

  int w = tid >> 6, l = tid & 63;
  int lr = l & 15, kg = l >> 4;
  int yloc = (w >> 1) * 16, xloc = (w & 1) * 16;

  // A fragments (validated conv1x1f convention: m=lr, k=kg*8+j)
  bf16x8 wf_[5][2];
#pragma unroll
  for (int r = 0; r < 5; r++)
#pragma unroll
    for (int g = 0; g < 2; g++)
      wf_[r][g] = *(const bf16x8*)(wA + ((r * 2 + g) * 16 + lr) * 32 + kg * 8);

  // per-lane B offsets per round (tap = 2r + (kg>>1), clamped; A is zero there)
  int offr[5];
#pragma unroll
  for (int r = 0; r < 5; r++) {
    int tap = 2 * r + (kg >> 1);
    if (tap > 8) tap = 8;
    int dy = tap / 3 - 1, dx = tap - (tap / 3) * 3 - 1;
    offr[r] = (dy * 34 + dx) * 12 + (kg & 1) * 4;
  }

  float bi[2][4];
#pragma unroll
  for (int g = 0; g < 2; g++)
#pragma unroll
    for (int rg = 0; rg < 4; rg++)
      bi[g][rg] = bias[g * 16 + kg * 4 + rg];

  __syncthreads();

  float s_[2][4], s2_[2][4];
#pragma unroll
  for (int g = 0; g < 2; g++)
#pragma unroll
    for (int rg = 0; rg < 4; rg++) { s_[g][rg] = 0.f; s2_[g][rg] = 0.f; }

  float* frb = fraw + (size_t)b * OPL * plane;
  for (int y = 0; y < 16; y++) {
    int rowbase = ((yloc + y + 1) * 34 + (xloc + lr + 1)) * 12;
    f32x4 a0 = {0, 0, 0, 0}, a1 = {0, 0, 0, 0};
#pragma unroll
    for (int r = 0; r < 5; r++) {
      bf16x8 bf_ = *(const bf16x8*)&sInT[rowbase + offr[r]];
      a0 = __builtin_amdgcn_mfma_f32_16x16x32_bf16(wf_[r][0], bf_, a0, 0, 0, 0);
      a1 = __builtin_amdgcn_mfma_f32_16x16x32_bf16(wf_[r][1], bf_, a1, 0, 0, 0);
    }
    int gy = by + yloc + y, gxp = bx + xloc + lr;
    size_t po = (size_t)gy * Hl + gxp;
#pragma unroll
    for (int rg = 0; rg < 4; rg++) {
      float v0 = a0[rg] + bi[0][rg];
      float v1 = a1[rg] + bi[1][rg];
      frb[(size_t)(kg * 4 + rg) * plane + po] = v0;
      frb[(size_t)(16 + kg * 4 + rg) * plane + po] = v1;
      s_[0][rg] += v0; s2_[0][rg] += v0 * v0;
      s_[1][rg] += v1; s2_[1][rg] += v1 * v1;
    }
  }
  // reduce across the 16-lane px group, then atomic per oc
#pragma unroll
  for (int g = 0; g < 2; g++)
#pragma unroll
    for (int rg = 0; rg < 4; rg++) {
      float s = s_[g][rg], s2 = s2_[g][rg];
#pragma unroll
      for (int m = 8; m >= 1; m >>= 1) {
        s += __shfl_xor(s, m);
        s2 += __shfl_xor(s2, m);
      }
      if (lr == 0) {
        int pc = b * OPL + g * 16 + kg * 4 + rg;
        atomicAdd(&sacc[pc * 2], s);
        atomicAdd(&sacc[pc * 2 + 1], s2);
      }
    }
}

// ---------------- level 0: normalize + prelu -> cat channels [0,32) ----------------
__global__ void k_norm0(const float* __restrict__ fraw, const float* __restrict__ sacc,
                        const float* __restrict__ a, bf16* __restrict__ cat) {
  int i = blockIdx.x * blockDim.x + threadIdx.x;
  if (i >= B * OPL * H * W) return;
  int pc = i >> 16;
  int b = pc >> 5, c = pc & 31;
  const float invN = 1.f / 65536.f;
  float mean = sacc[pc * 2] * invN;
  float var = sacc[pc * 2 + 1] * invN - mean * mean;
  float rstd = rsqrtf(fmaxf(var, 0.f) + EPS);
  float v = (fraw[i] - mean) * rstd;
  float al = a[0];
  v = v >= 0.f ? v : al * v;
  cat[(((size_t)(b * OC + c)) << 16) + (i & 65535)] = __float2bfloat16(v);
}

// ---------------- levels 1/2: normalize + prelu + bilinear up ----------------
__global__ void k_upnorm(const float* __restrict__ fraw, const float* __restrict__ sacc,
                         const float* __restrict__ a, bf16* __restrict__ cat,
                         int Hl, int r, int cofs, float invN) {
  int i = blockIdx.x * blockDim.x + threadIdx.x;
  if (i >= B * OPL * H * W) return;
  int x = i & 255, y = (i >> 8) & 255;
  int pc = i >> 16;
  int b = pc >> 5, c = pc & 31;
  float mean = sacc[pc * 2] * invN;
  float var = sacc[pc * 2 + 1] * invN - mean * mean;
  float rstd = rsqrtf(fmaxf(var, 0.f) + EPS);
  float al = a[0];
  int x0, x1, y0, y1; float wx, wy;
  bil_coord(x, r, Hl, x0, x1, wx);
  bil_coord(y, r, Hl, y0, y1, wy);
  const float* ip = fraw + (size_t)pc * Hl * Hl;
  float v00 = ip[(size_t)y0 * Hl + x0], v01 = ip[(size_t)y0 * Hl + x1];
  float v10 = ip[(size_t)y1 * Hl + x0], v11 = ip[(size_t)y1 * Hl + x1];
  v00 = (v00 - mean) * rstd; v00 = v00 >= 0.f ? v00 : al * v00;
  v01 = (v01 - mean) * rstd; v01 = v01 >= 0.f ? v01 : al * v01;
  v10 = (v10 - mean) * rstd; v10 = v10 >= 0.f ? v10 : al * v10;
  v11 = (v11 - mean) * rstd; v11 = v11 >= 0.f ? v11 : al * v11;
  float v = (1.f - wy) * ((1.f - wx) * v00 + wx * v01)
          + wy * ((1.f - wx) * v10 + wx * v11);
  cat[(((size_t)(b * OC + cofs + c)) << 16) + (y << 8) + x] = __float2bfloat16(v);
}

// ---------------- weights fp32 -> bf16 ----------------
__global__ void k_wprep(const float* __restrict__ wf, bf16* __restrict__ wbf) {
  int i = blockIdx.x * 256 + threadIdx.x;
  if (i < OC * OC) wbf[i] = __float2bfloat16(wf[i]);
}

// ---------------- second moments of cat per batch: G2 = cat*cat^T, musum ----------------
__global__ void __launch_bounds__(384) k_moments(const bf16* __restrict__ cat,
    float* __restrict__ G2, float* __restrict__ musum) {
  int b = blockIdx.x >> 5;
  int chunk = blockIdx.x & 31;
  int ti = threadIdx.x >> 6;
  int l = threadIdx.x & 63;
  int lr = l & 15, kg = l >> 4;
  const bf16* base = cat + ((size_t)(b * OC) << 16);
  f32x4 acc0 = {0,0,0,0}, acc1 = {0,0,0,0}, acc2 = {0,0,0,0};
  f32x4 acc3 = {0,0,0,0}, acc4 = {0,0,0,0}, acc5 = {0,0,0,0};
  f32x4 accO = {0,0,0,0};
  bf16x8 ones;
#pragma unroll
  for (int j = 0; j < 8; j++) ones[j] = (short)0x3F80;
  int p0 = chunk * 2048 + kg * 8;
  const bf16* arow = base + (((size_t)(ti * 16 + lr)) << 16);
#pragma unroll 2
  for (int s = 0; s < 64; s++) {
    int p = p0 + s * 32;
    bf16x8 fa = *(const bf16x8*)(arow + p);
    bf16x8 f0 = *(const bf16x8*)(base + (((size_t)(0 + lr)) << 16) + p);
    bf16x8 f1 = *(const bf16x8*)(base + (((size_t)(16 + lr)) << 16) + p);
    bf16x8 f2 = *(const bf16x8*)(base + (((size_t)(32 + lr)) << 16) + p);
    bf16x8 f3 = *(const bf16x8*)(base + (((size_t)(48 + lr)) << 16) + p);
    bf16x8 f4 = *(const bf16x8*)(base + (((size_t)(64 + lr)) << 16) + p);
    bf16x8 f5 = *(const bf16x8*)(base + (((size_t)(80 + lr)) << 16) + p);
    acc0 = __builtin_amdgcn_mfma_f32_16x16x32_bf16(fa, f0, acc0, 0, 0, 0);
    acc1 = __builtin_amdgcn_mfma_f32_16x16x32_bf16(fa, f1, acc1, 0, 0, 0);
    acc2 = __builtin_amdgcn_mfma_f32_16x16x32_bf16(fa, f2, acc2, 0, 0, 0);
    acc3 = __builtin_amdgcn_mfma_f32_16x16x32_bf16(fa, f3, acc3, 0, 0, 0);
    acc4 = __builtin_amdgcn_mfma_f32_16x16x32_bf16(fa, f4, acc4, 0, 0, 0);
    acc5 = __builtin_amdgcn_mfma_f32_16x16x32_bf16(fa, f5, acc5, 0, 0, 0);
    accO = __builtin_amdgcn_mfma_f32_16x16x32_bf16(fa, ones, accO, 0, 0, 0);
  }
  f32x4 accs[6] = {acc0, acc1, acc2, acc3, acc4, acc5};
#pragma unroll
  for (int t = 0; t < 6; t++)
#pragma unroll
    for (int r = 0; r < 4; r++) {
      int i = ti * 16 + kg * 4 + r, j = t * 16 + lr;
      atomicAdd(&G2[(size_t)(b * OC + i) * OC + j], accs[t][r]);
    }
#pragma unroll
  for (int r = 0; r < 4; r++) {
    int i = ti * 16 + kg * 4 + r;
    if (lr == 0) atomicAdd(&musum[b * OC + i], accO[r]);
  }
}

// ---------------- combine: per (b,oc) scale/shift for fused IN ----------------
__global__ void __launch_bounds__(128) k_statsF(const float* __restrict__ G2,
    const float* __restrict__ musum, const float* __restrict__ wf,
    const float* __restrict__ bfv, float* __restrict__ scale,
    float* __restrict__ shift) {
  int oc = blockIdx.x, b = blockIdx.y;
  int j = threadIdx.x;
  float quad = 0.f, lin = 0.f;
  if (j < OC) {
    float wj = __bfloat162float(__float2bfloat16(wf[oc * OC + j]));
    const float* g = G2 + (size_t)(b * OC) * OC + j;
    float inner = 0.f;
#pragma unroll 4
    for (int i = 0; i < OC; i++) {
      float wi = __bfloat162float(__float2bfloat16(wf[oc * OC + i]));
      inner = fmaf(wi, g[(size_t)i * OC], inner);
    }
    quad = wj * inner;
    lin = wj * musum[b * OC + j];
  }
  __shared__ float rq[2], rl[2];
  for (int off = 32; off > 0; off >>= 1) {
    quad += __shfl_down(quad, off);
    lin += __shfl_down(lin, off);
  }
  if ((threadIdx.x & 63) == 0) { rq[threadIdx.x >> 6] = quad; rl[threadIdx.x >> 6] = lin; }
  __syncthreads();
  if (threadIdx.x == 0) {
    float Q = rq[0] + rq[1], L = rl[0] + rl[1];
    const float invN = 1.f / 65536.f;
    float bias = bfv[oc];
    float mean = L * invN + bias;
    float e2 = Q * invN + 2.f * bias * (L * invN) + bias * bias;
    float var = e2 - mean * mean;
    float rstd = rsqrtf(fmaxf(var, 0.f) + EPS);
    scale[b * OC + oc] = rstd;
    shift[b * OC + oc] = (bias - mean) * rstd;
  }
}

// ---------------- fused final conv1x1 (MFMA) + IN + prelu -> d_out ----------------
constexpr int CROW = 52;
__global__ void __launch_bounds__(256) k_conv1x1f(const bf16* __restrict__ cat,
    const bf16* __restrict__ wbf, const float* __restrict__ scale,
    const float* __restrict__ shift, const float* __restrict__ af,
    float* __restrict__ out) {
  __shared__ unsigned int sT[128 * CROW];
  int b = blockIdx.x >> 6;
  int px0 = (blockIdx.x & 63) * 1024;
  int tid = threadIdx.x, w = tid >> 6, l = tid & 63;
  int lr = l & 15, kg = l >> 4;
  bf16x8 wf_[6][3];
#pragma unroll
  for (int t = 0; t < 6; t++)
#pragma unroll
    for (int ks = 0; ks < 3; ks++)
      wf_[t][ks] = *(const bf16x8*)(wbf + (t * 16 + lr) * OC + ks * 32 + kg * 8);
  float al = af[0];
  int bo = b * OC;
  float sc[6][4], sh[6][4];
#pragma unroll
  for (int t = 0; t < 6; t++)
#pragma unroll
    for (int r = 0; r < 4; r++) {
      int oc = t * 16 + kg * 4 + r;
      sc[t][r] = scale[bo + oc];
      sh[t][r] = shift[bo + oc];
    }
  const bf16* cb = cat + ((size_t)bo << 16);
  for (int round = 0; round < 8; round++) {
    int rp0 = px0 + round * 128;
    __syncthreads();
#pragma unroll
    for (int k = 0; k < 3; k++) {
      int it = tid + k * 256;
      int p = it % 48, g = it / 48;
      const bf16* r0 = cb + (((size_t)(2 * p)) << 16) + rp0 + g * 8;
      bf16x8 a = *(const bf16x8*)r0;
      bf16x8 c = *(const bf16x8*)(r0 + 65536);
#pragma unroll
      for (int j = 0; j < 8; j++) {
        unsigned int d = (unsigned int)(unsigned short)a[j]
                       | ((unsigned int)(unsigned short)c[j] << 16);
        sT[(g * 8 + j) * CROW + p] = d;
      }
    }
    __syncthreads();
#pragma unroll
    for (int pt = 0; pt < 2; pt++) {
      int tloc = w * 2 + pt;
      int pl = tloc * 16 + lr;
      f32x4 a0 = {0,0,0,0}, a1 = {0,0,0,0}, a2 = {0,0,0,0};
      f32x4 a3 = {0,0,0,0}, a4 = {0,0,0,0}, a5 = {0,0,0,0};
#pragma unroll
      for (int ks = 0; ks < 3; ks++) {
        bf16x8 bf_ = *(const bf16x8*)&sT[pl * CROW + ks * 16 + kg * 4];
        a0 = __builtin_amdgcn_mfma_f32_16x16x32_bf16(wf_[0][ks], bf_, a0, 0, 0, 0);
        a1 = __builtin_amdgcn_mfma_f32_16x16x32_bf16(wf_[1][ks], bf_, a1, 0, 0, 0);
        a2 = __builtin_amdgcn_mfma_f32_16x16x32_bf16(wf_[2][ks], bf_, a2, 0, 0, 0);
        a3 = __builtin_amdgcn_mfma_f32_16x16x32_bf16(wf_[3][ks], bf_, a3, 0, 0, 0);
        a4 = __builtin_amdgcn_mfma_f32_16x16x32_bf16(wf_[4][ks], bf_, a4, 0, 0, 0);
        a5 = __builtin_amdgcn_mfma_f32_16x16x32_bf16(wf_[5][ks], bf_, a5, 0, 0, 0);
      }
      f32x4 accs[6] = {a0, a1, a2, a3, a4, a5};
      int px = rp0 + tloc * 16 + lr;
#pragma unroll
      for (int t = 0; t < 6; t++)
#pragma unroll
        for (int r = 0; r < 4; r++) {
          int oc = t * 16 + kg * 4 + r;
          float v = accs[t][r] * sc[t][r] + sh[t][r];
          v = v >= 0.f ? v : al * v;
          out[((size_t)(bo + oc) << 16) + px] = v;
        }
    }
  }
}

extern "C" void kernel_launch(void* const* d_in, const int* in_sizes, int n_in,
                              void* d_out, int out_size, void* d_ws, size_t ws_size,
                              hipStream_t stream) {
  const float* x   = (const float*)d_in[0];
  const float* w[3]  = {(const float*)d_in[1], (const float*)d_in[4], (const float*)d_in[7]};
  const float* bb[3] = {(const float*)d_in[2], (const float*)d_in[5], (const float*)d_in[8]};
  const float* aa[3] = {(const float*)d_in[3], (const float*)d_in[6], (const float*)d_in[9]};
  const float* wfp = (const float*)d_in[10];
  const float* bfv = (const float*)d_in[11];
  const float* af  = (const float*)d_in[12];
  float* out = (float*)d_out;

  char* ws = (char*)d_ws;
  bf16*  cat  = (bf16*)ws;
  bf16*  wav  = (bf16*)(ws + 201326592ull);
  float* fraw = (float*)(ws + 201326592ull + 25165824ull);
  float* bands = fraw;
  float* cur1 = (float*)(ws + 201326592ull + 25165824ull + 134217728ull);
  float* cur2 = cur1 + 786432;
  float* sacc = cur2 + 196608;          // 3 levels x 1024 floats
  bf16*  wA3  = (bf16*)(sacc + 3072);   // 3 x 5120 bf16
  float* G2    = cur1;                  // alias (cur1 dead by then)
  float* musum = G2 + 16 * OC * OC;
  float* scale = musum + 16 * OC;
  float* shift = scale + 16 * OC;
  bf16*  wbf   = (bf16*)(shift + 16 * OC);

  auto cdiv = [](int a, int b) { return (a + b - 1) / b; };

  hipMemsetAsync(sacc, 0, 3072 * sizeof(float), stream);
  k_wprep3<<<60, 256, 0, stream>>>(w[0], w[1], w[2], wA3);

  k_avgpool<<<cdiv(B * CIN * 128 * 128, 256), 256, 0, stream>>>(x, cur1, 128, 128);
  k_avgpool<<<cdiv(B * CIN * 64 * 64, 256), 256, 0, stream>>>(cur1, cur2, 64, 64);

  const float* curp[3] = {x, cur1, cur2};
  int Hls[3] = {256, 128, 64};
  for (int l = 0; l < 3; l++) {
    int Hl = Hls[l], h2 = Hl / 2;
    k_bands<<<cdiv(B * CIN * h2 * h2, 256), 256, 0, stream>>>(curp[l], bands, Hl, Hl);
    k_upsample_b<<<cdiv(B * WAVC * Hl * Hl, 256), 256, 0, stream>>>(bands, wav, WAVC, h2, h2);
    int ntx = Hl / 32;
    dim3 g3(ntx * ntx, B);
    k_conv3m<<<g3, 256, 0, stream>>>(wav, wA3 + l * 5120, bb[l], fraw,
                                     sacc + l * 1024, Hl, ntx);
    if (l == 0)
      k_norm0<<<cdiv(B * OPL * H * W, 256), 256, 0, stream>>>(fraw, sacc, aa[0], cat);
    else
      k_upnorm<<<cdiv(B * OPL * H * W, 256), 256, 0, stream>>>(fraw, sacc + l * 1024,
          aa[l], cat, Hl, 256 / Hl, l * OPL, 1.f / (float)(Hl * Hl));
  }

  k_wprep<<<36, 256, 0, stream>>>(wfp, wbf);
  hipMemsetAsync(G2, 0, (size_t)(16 * OC * OC + 16 * OC) * sizeof(float), stream);
  k_moments<<<16 * 32, 384, 0, stream>>>(cat, G2, musum);
  dim3 gs(OC, B);
  k_statsF<<<gs, 128, 0, stream>>>(G2, musum, wfp, bfv, scale, shift);
  k_conv1x1f<<<16 * 64, 256, 0, stream>>>(cat, wbf, scale, shift, af, out);
}

// Round 4
// 671.458 us; speedup vs baseline: 2.0284x; 1.2317x over previous
//
#include <hip/hip_runtime.h>
#include <hip/hip_bf16.h>

typedef __hip_bfloat16 bf16;
typedef __attribute__((ext_vector_type(8))) short bf16x8;
typedef __attribute__((ext_vector_type(4))) float f32x4;

constexpr int B = 16, CIN = 3, H = 256, W = 256;
constexpr int OPL = 32, WAVC = 12, OC = 96;
#define EPS 1e-5f

// ---------------- avg pool 2x2 ----------------
__global__ void k_avgpool(const float* __restrict__ in, float* __restrict__ out,
                          int Ho, int Wo) {
  int n = B * CIN * Ho * Wo;
  int i = blockIdx.x * blockDim.x + threadIdx.x;
  if (i >= n) return;
  int x = i % Wo, y = (i / Wo) % Ho, p = i / (Wo * Ho);
  int Wi = Wo * 2;
  const float* ip = in + (size_t)p * (Ho * 2) * Wi + (size_t)(2 * y) * Wi + 2 * x;
  out[i] = 0.25f * (ip[0] + ip[1] + ip[Wi] + ip[Wi + 1]);
}

// jax.image.resize bilinear: s=(o+0.5)/r-0.5, edge renormalize == clamp
__device__ inline void bil_coord(int o, int r, int n, int& i0, int& i1, float& w1) {
  float s = (o + 0.5f) / (float)r - 0.5f;
  float fl = floorf(s);
  w1 = s - fl;
  int y0 = (int)fl;
  i0 = y0 < 0 ? 0 : y0;
  i1 = (y0 + 1 > n - 1) ? (n - 1) : (y0 + 1);
}

// ---------------- conv3x3 weight prep: per level, K-packed A fragments ----------------
__global__ void k_wprep3(const float* __restrict__ w0, const float* __restrict__ w1,
                         const float* __restrict__ w2, bf16* __restrict__ wA) {
  int i = blockIdx.x * 256 + threadIdx.x;
  if (i >= 3 * 5120) return;
  int l = i / 5120, rem = i % 5120;
  int entry = rem >> 5, kk = rem & 31;
  int r = entry >> 5, g = (entry >> 4) & 1, lr = entry & 15;
  int t = kk >> 4, ic = kk & 15;
  int tap = 2 * r + t;
  const float* wl = l == 0 ? w0 : (l == 1 ? w1 : w2);
  float v = 0.f;
  if (tap <= 8 && ic < 12) v = wl[((g * 16 + lr) * 12 + ic) * 9 + tap];
  wA[i] = __float2bfloat16(v);
}

// ---------------- FUSED: Haar bands + bilinear x2 up + conv3x3 (MFMA) + stats -------
// block: 256 thr (4 waves), 32x32 output tile.
// LDS pool: sInT (34*34*12 dw, head aliased as sCur 3x36x36 f32) + sBands 18*18*12 f32.
__global__ void __launch_bounds__(256) k_fused3(const float* __restrict__ cur,
    const bf16* __restrict__ wA, const float* __restrict__ bias,
    bf16* __restrict__ fraw, float* __restrict__ sacc, int Hl, int ntx) {
  __shared__ unsigned int sPool[34 * 34 * 12 + 18 * 18 * 12];
  unsigned int* sInT = sPool;                         // [yy][xx][12]
  float* sCur = (float*)sPool;                        // [3][36][36]  (aliases sInT head)
  float* sBands = (float*)(sPool + 34 * 34 * 12);     // [ys][xs][3][4]

  int tile = blockIdx.x, b = blockIdx.y;
  int by = (tile / ntx) * 32, bx = (tile % ntx) * 32;
  int tid = threadIdx.x;
  int h2 = Hl >> 1;
  size_t plane = (size_t)Hl * Hl;

  // --- per-thread MFMA constants (no LDS dependency) ---
  int w = tid >> 6, l = tid & 63;
  int lr = l & 15, kg = l >> 4;
  int yloc = (w >> 1) * 16, xloc = (w & 1) * 16;
  bf16x8 wf_[5][2];
#pragma unroll
  for (int r = 0; r < 5; r++)
#pragma unroll
    for (int g = 0; g < 2; g++)
      wf_[r][g] = *(const bf16x8*)(wA + ((r * 2 + g) * 16 + lr) * 32 + kg * 8);
  int offr[5];
#pragma unroll
  for (int r = 0; r < 5; r++) {
    int tap = 2 * r + (kg >> 1);
    if (tap > 8) tap = 8;
    int dy = tap / 3 - 1, dx = tap - (tap / 3) * 3 - 1;
    offr[r] = (dy * 34 + dx) * 12 + (kg & 1) * 4;
  }
  float bi[2][4];
#pragma unroll
  for (int g = 0; g < 2; g++)
#pragma unroll
    for (int rg = 0; rg < 4; rg++)
      bi[g][rg] = bias[g * 16 + kg * 4 + rg];

  // --- phase A: load cur tile [by-2, by+33] x [bx-2, bx+33], clamped ---
  const float* cb = cur + (size_t)(b * CIN) * plane;
  for (int it = tid; it < 3 * 36 * 36; it += 256) {
    int xx = it % 36, rest = it / 36, yy = rest % 36, c = rest / 36;
    int gy = by - 2 + yy, gx = bx - 2 + xx;
    gy = gy < 0 ? 0 : (gy > Hl - 1 ? Hl - 1 : gy);
    gx = gx < 0 ? 0 : (gx > Hl - 1 ? Hl - 1 : gx);
    sCur[it] = cb[c * plane + (size_t)gy * Hl + gx];
  }
  __syncthreads();

  // --- phase B: Haar bands tile 18x18 (band row base = by/2 - 1) ---
  for (int it = tid; it < 18 * 18 * 3; it += 256) {
    int c = it % 3, rest = it / 3, xs = rest % 18, ys = rest / 18;
    const float* cp = sCur + c * 1296 + (2 * ys) * 36 + 2 * xs;
    float e = cp[0], f = cp[1], g = cp[36], h = cp[37];
    f32x4 v;
    v[0] = (e + f + g + h) * 0.5f;
    v[1] = (e + f - g - h) * 0.5f;
    v[2] = (e - f + g - h) * 0.5f;
    v[3] = (e - f - g + h) * 0.5f;
    *(f32x4*)&sBands[(ys * 18 + xs) * 12 + c * 4] = v;
  }
  __syncthreads();

  // --- phase C: bilinear x2 expand into packed sInT (+ zero K-pad dwords) ---
  int yb_base = (by >> 1) - 1, xb_base = (bx >> 1) - 1;
  for (int it = tid; it < 34 * 34 * 3; it += 256) {
    int c = it % 3, rest = it / 3, xx = rest % 34, yy = rest / 34;
    int base = (yy * 34 + xx) * 12 + c * 2;
    int Y = by - 1 + yy, X = bx - 1 + xx;
    if (Y < 0 || Y >= Hl || X < 0 || X >= Hl) {
      sInT[base] = 0; sInT[base + 1] = 0;
      continue;
    }
    int my = Y >> 1, dy = Y & 1;
    int y0 = my - 1 + dy;
    float wy = dy ? 0.25f : 0.75f;
    int y0c = y0 < 0 ? 0 : y0, y1c = (y0 + 1 > h2 - 1) ? h2 - 1 : y0 + 1;
    int ys0 = y0c - yb_base, ys1 = y1c - yb_base;
    int mx = X >> 1, dx = X & 1;
    int x0 = mx - 1 + dx;
    float wx = dx ? 0.25f : 0.75f;
    int x0c = x0 < 0 ? 0 : x0, x1c = (x0 + 1 > h2 - 1) ? h2 - 1 : x0 + 1;
    int xs0 = x0c - xb_base, xs1 = x1c - xb_base;
    f32x4 c00 = *(const f32x4*)&sBands[(ys0 * 18 + xs0) * 12 + c * 4];
    f32x4 c01 = *(const f32x4*)&sBands[(ys0 * 18 + xs1) * 12 + c * 4];
    f32x4 c10 = *(const f32x4*)&sBands[(ys1 * 18 + xs0) * 12 + c * 4];
    f32x4 c11 = *(const f32x4*)&sBands[(ys1 * 18 + xs1) * 12 + c * 4];
    f32x4 v0 = c00 + wx * (c01 - c00);
    f32x4 v1 = c10 + wx * (c11 - c10);
    f32x4 v = v0 + wy * (v1 - v0);
    unsigned int d0 = (unsigned int)__bfloat16_as_ushort(__float2bfloat16(v[0]))
                    | ((unsigned int)__bfloat16_as_ushort(__float2bfloat16(v[1])) << 16);
    unsigned int d1 = (unsigned int)__bfloat16_as_ushort(__float2bfloat16(v[2]))
                    | ((unsigned int)__bfloat16_as_ushort(__float2bfloat16(v[3])) << 16);
    sInT[base] = d0;
    sInT[base + 1] = d1;
  }
  for (int it = tid; it < 34 * 34; it += 256) {
    sInT[it * 12 + 6] = 0;
    sInT[it * 12 + 7] = 0;
  }
  __syncthreads();

  // --- MFMA conv + bf16 store + fused stats ---
  float s_[2][4], s2_[2][4];
#pragma unroll
  for (int g = 0; g < 2; g++)
#pragma unroll
    for (int rg = 0; rg < 4; rg++) { s_[g][rg] = 0.f; s2_[g][rg] = 0.f; }

  bf16* frb = fraw + (size_t)b * OPL * plane;
  for (int y = 0; y < 16; y++) {
    int rowbase = ((yloc + y + 1) * 34 + (xloc + lr + 1)) * 12;
    f32x4 a0 = {0, 0, 0, 0}, a1 = {0, 0, 0, 0};
#pragma unroll
    for (int r = 0; r < 5; r++) {
      bf16x8 bf_ = *(const bf16x8*)&sInT[rowbase + offr[r]];
      a0 = __builtin_amdgcn_mfma_f32_16x16x32_bf16(wf_[r][0], bf_, a0, 0, 0, 0);
      a1 = __builtin_amdgcn_mfma_f32_16x16x32_bf16(wf_[r][1], bf_, a1, 0, 0, 0);
    }
    int gy = by + yloc + y, gxp = bx + xloc + lr;
    size_t po = (size_t)gy * Hl + gxp;
#pragma unroll
    for (int rg = 0; rg < 4; rg++) {
      bf16 vb0 = __float2bfloat16(a0[rg] + bi[0][rg]);
      bf16 vb1 = __float2bfloat16(a1[rg] + bi[1][rg]);
      frb[(size_t)(kg * 4 + rg) * plane + po] = vb0;
      frb[(size_t)(16 + kg * 4 + rg) * plane + po] = vb1;
      float v0 = __bfloat162float(vb0), v1 = __bfloat162float(vb1);
      s_[0][rg] += v0; s2_[0][rg] += v0 * v0;
      s_[1][rg] += v1; s2_[1][rg] += v1 * v1;
    }
  }
#pragma unroll
  for (int g = 0; g < 2; g++)
#pragma unroll
    for (int rg = 0; rg < 4; rg++) {
      float s = s_[g][rg], s2 = s2_[g][rg];
#pragma unroll
      for (int m = 8; m >= 1; m >>= 1) {
        s += __shfl_xor(s, m);
        s2 += __shfl_xor(s2, m);
      }
      if (lr == 0) {
        int pc = b * OPL + g * 16 + kg * 4 + rg;
        atomicAdd(&sacc[pc * 2], s);
        atomicAdd(&sacc[pc * 2 + 1], s2);
      }
    }
}

// ---------------- level 0: normalize + prelu -> cat channels [0,32), 8 px/thread ----
__global__ void k_norm0(const bf16* __restrict__ fraw, const float* __restrict__ sacc,
                        const float* __restrict__ a, bf16* __restrict__ cat) {
  int t = blockIdx.x * blockDim.x + threadIdx.x;
  if (t >= B * OPL * H * W / 8) return;
  int i = t * 8;
  int pc = i >> 16;
  int b = pc >> 5, c = pc & 31;
  const float invN = 1.f / 65536.f;
  float mean = sacc[pc * 2] * invN;
  float var = sacc[pc * 2 + 1] * invN - mean * mean;
  float rstd = rsqrtf(fmaxf(var, 0.f) + EPS);
  float al = a[0];
  bf16x8 in = *(const bf16x8*)(fraw + i);
  bf16x8 o;
#pragma unroll
  for (int j = 0; j < 8; j++) {
    float v = __bfloat162float(__ushort_as_bfloat16((unsigned short)in[j]));
    v = (v - mean) * rstd;
    v = v >= 0.f ? v : al * v;
    o[j] = (short)__bfloat16_as_ushort(__float2bfloat16(v));
  }
  *(bf16x8*)(cat + (((size_t)(b * OC + c)) << 16) + (i & 65535)) = o;
}

// ---------------- levels 1/2: normalize + prelu + bilinear up, 2 px/thread ----------
__global__ void k_upnorm(const bf16* __restrict__ fraw, const float* __restrict__ sacc,
                         const float* __restrict__ a, bf16* __restrict__ cat,
                         int Hl, int r, int cofs, float invN) {
  int t = blockIdx.x * blockDim.x + threadIdx.x;
  if (t >= B * OPL * H * W / 2) return;
  int x2 = (t & 127) * 2;
  int y = (t >> 7) & 255;
  int pc = t >> 15;
  int b = pc >> 5, c = pc & 31;
  float mean = sacc[pc * 2] * invN;
  float var = sacc[pc * 2 + 1] * invN - mean * mean;
  float rstd = rsqrtf(fmaxf(var, 0.f) + EPS);
  float al = a[0];
  int y0, y1; float wy;
  bil_coord(y, r, Hl, y0, y1, wy);
  const bf16* ip = fraw + (size_t)pc * Hl * Hl;
  unsigned int packed = 0;
#pragma unroll
  for (int k = 0; k < 2; k++) {
    int x0, x1; float wx;
    bil_coord(x2 + k, r, Hl, x0, x1, wx);
    float v00 = __bfloat162float(ip[(size_t)y0 * Hl + x0]);
    float v01 = __bfloat162float(ip[(size_t)y0 * Hl + x1]);
    float v10 = __bfloat162float(ip[(size_t)y1 * Hl + x0]);
    float v11 = __bfloat162float(ip[(size_t)y1 * Hl + x1]);
    v00 = (v00 - mean) * rstd; v00 = v00 >= 0.f ? v00 : al * v00;
    v01 = (v01 - mean) * rstd; v01 = v01 >= 0.f ? v01 : al * v01;
    v10 = (v10 - mean) * rstd; v10 = v10 >= 0.f ? v10 : al * v10;
    v11 = (v11 - mean) * rstd; v11 = v11 >= 0.f ? v11 : al * v11;
    float v = (1.f - wy) * ((1.f - wx) * v00 + wx * v01)
            + wy * ((1.f - wx) * v10 + wx * v11);
    packed |= (unsigned int)__bfloat16_as_ushort(__float2bfloat16(v)) << (16 * k);
  }
  *(unsigned int*)((unsigned short*)cat + (((size_t)(b * OC + cofs + c)) << 16)
                   + (y << 8) + x2) = packed;
}

// ---------------- weights fp32 -> bf16 ----------------
__global__ void k_wprep(const float* __restrict__ wf, bf16* __restrict__ wbf) {
  int i = blockIdx.x * 256 + threadIdx.x;
  if (i < OC * OC) wbf[i] = __float2bfloat16(wf[i]);
}

// ---------------- second moments of cat per batch: G2 = cat*cat^T, musum ----------------
__global__ void __launch_bounds__(384) k_moments(const bf16* __restrict__ cat,
    float* __restrict__ G2, float* __restrict__ musum) {
  int b = blockIdx.x >> 5;
  int chunk = blockIdx.x & 31;
  int ti = threadIdx.x >> 6;
  int l = threadIdx.x & 63;
  int lr = l & 15, kg = l >> 4;
  const bf16* base = cat + ((size_t)(b * OC) << 16);
  f32x4 acc0 = {0,0,0,0}, acc1 = {0,0,0,0}, acc2 = {0,0,0,0};
  f32x4 acc3 = {0,0,0,0}, acc4 = {0,0,0,0}, acc5 = {0,0,0,0};
  f32x4 accO = {0,0,0,0};
  bf16x8 ones;
#pragma unroll
  for (int j = 0; j < 8; j++) ones[j] = (short)0x3F80;
  int p0 = chunk * 2048 + kg * 8;
  const bf16* arow = base + (((size_t)(ti * 16 + lr)) << 16);
#pragma unroll 2
  for (int s = 0; s < 64; s++) {
    int p = p0 + s * 32;
    bf16x8 fa = *(const bf16x8*)(arow + p);
    bf16x8 f0 = *(const bf16x8*)(base + (((size_t)(0 + lr)) << 16) + p);
    bf16x8 f1 = *(const bf16x8*)(base + (((size_t)(16 + lr)) << 16) + p);
    bf16x8 f2 = *(const bf16x8*)(base + (((size_t)(32 + lr)) << 16) + p);
    bf16x8 f3 = *(const bf16x8*)(base + (((size_t)(48 + lr)) << 16) + p);
    bf16x8 f4 = *(const bf16x8*)(base + (((size_t)(64 + lr)) << 16) + p);
    bf16x8 f5 = *(const bf16x8*)(base + (((size_t)(80 + lr)) << 16) + p);
    acc0 = __builtin_amdgcn_mfma_f32_16x16x32_bf16(fa, f0, acc0, 0, 0, 0);
    acc1 = __builtin_amdgcn_mfma_f32_16x16x32_bf16(fa, f1, acc1, 0, 0, 0);
    acc2 = __builtin_amdgcn_mfma_f32_16x16x32_bf16(fa, f2, acc2, 0, 0, 0);
    acc3 = __builtin_amdgcn_mfma_f32_16x16x32_bf16(fa, f3, acc3, 0, 0, 0);
    acc4 = __builtin_amdgcn_mfma_f32_16x16x32_bf16(fa, f4, acc4, 0, 0, 0);
    acc5 = __builtin_amdgcn_mfma_f32_16x16x32_bf16(fa, f5, acc5, 0, 0, 0);
    accO = __builtin_amdgcn_mfma_f32_16x16x32_bf16(fa, ones, accO, 0, 0, 0);
  }
  f32x4 accs[6] = {acc0, acc1, acc2, acc3, acc4, acc5};
#pragma unroll
  for (int t = 0; t < 6; t++)
#pragma unroll
    for (int r = 0; r < 4; r++) {
      int i = ti * 16 + kg * 4 + r, j = t * 16 + lr;
      atomicAdd(&G2[(size_t)(b * OC + i) * OC + j], accs[t][r]);
    }
#pragma unroll
  for (int r = 0; r < 4; r++) {
    int i = ti * 16 + kg * 4 + r;
    if (lr == 0) atomicAdd(&musum[b * OC + i], accO[r]);
  }
}

// ---------------- combine: per (b,oc) scale/shift for fused IN ----------------
__global__ void __launch_bounds__(128) k_statsF(const float* __restrict__ G2,
    const float* __restrict__ musum, const float* __restrict__ wf,
    const float* __restrict__ bfv, float* __restrict__ scale,
    float* __restrict__ shift) {
  int oc = blockIdx.x, b = blockIdx.y;
  int j = threadIdx.x;
  float quad = 0.f, lin = 0.f;
  if (j < OC) {
    float wj = __bfloat162float(__float2bfloat16(wf[oc * OC + j]));
    const float* g = G2 + (size_t)(b * OC) * OC + j;
    float inner = 0.f;
#pragma unroll 4
    for (int i = 0; i < OC; i++) {
      float wi = __bfloat162float(__float2bfloat16(wf[oc * OC + i]));
      inner = fmaf(wi, g[(size_t)i * OC], inner);
    }
    quad = wj * inner;
    lin = wj * musum[b * OC + j];
  }
  __shared__ float rq[2], rl[2];
  for (int off = 32; off > 0; off >>= 1) {
    quad += __shfl_down(quad, off);
    lin += __shfl_down(lin, off);
  }
  if ((threadIdx.x & 63) == 0) { rq[threadIdx.x >> 6] = quad; rl[threadIdx.x >> 6] = lin; }
  __syncthreads();
  if (threadIdx.x == 0) {
    float Q = rq[0] + rq[1], L = rl[0] + rl[1];
    const float invN = 1.f / 65536.f;
    float bias = bfv[oc];
    float mean = L * invN + bias;
    float e2 = Q * invN + 2.f * bias * (L * invN) + bias * bias;
    float var = e2 - mean * mean;
    float rstd = rsqrtf(fmaxf(var, 0.f) + EPS);
    scale[b * OC + oc] = rstd;
    shift[b * OC + oc] = (bias - mean) * rstd;
  }
}

// ---------------- fused final conv1x1 (MFMA) + IN + prelu -> d_out ----------------
constexpr int CROW = 52;
__global__ void __launch_bounds__(256) k_conv1x1f(const bf16* __restrict__ cat,
    const bf16* __restrict__ wbf, const float* __restrict__ scale,
    const float* __restrict__ shift, const float* __restrict__ af,
    float* __restrict__ out) {
  __shared__ unsigned int sT[128 * CROW];
  int b = blockIdx.x >> 6;
  int px0 = (blockIdx.x & 63) * 1024;
  int tid = threadIdx.x, w = tid >> 6, l = tid & 63;
  int lr = l & 15, kg = l >> 4;
  bf16x8 wf_[6][3];
#pragma unroll
  for (int t = 0; t < 6; t++)
#pragma unroll
    for (int ks = 0; ks < 3; ks++)
      wf_[t][ks] = *(const bf16x8*)(wbf + (t * 16 + lr) * OC + ks * 32 + kg * 8);
  float al = af[0];
  int bo = b * OC;
  float sc[6][4], sh[6][4];
#pragma unroll
  for (int t = 0; t < 6; t++)
#pragma unroll
    for (int r = 0; r < 4; r++) {
      int oc = t * 16 + kg * 4 + r;
      sc[t][r] = scale[bo + oc];
      sh[t][r] = shift[bo + oc];
    }
  const bf16* cb = cat + ((size_t)bo << 16);
  for (int round = 0; round < 8; round++) {
    int rp0 = px0 + round * 128;
    __syncthreads();
#pragma unroll
    for (int k = 0; k < 3; k++) {
      int it = tid + k * 256;
      int p = it % 48, g = it / 48;
      const bf16* r0 = cb + (((size_t)(2 * p)) << 16) + rp0 + g * 8;
      bf16x8 a = *(const bf16x8*)r0;
      bf16x8 c = *(const bf16x8*)(r0 + 65536);
#pragma unroll
      for (int j = 0; j < 8; j++) {
        unsigned int d = (unsigned int)(unsigned short)a[j]
                       | ((unsigned int)(unsigned short)c[j] << 16);
        sT[(g * 8 + j) * CROW + p] = d;
      }
    }
    __syncthreads();
#pragma unroll
    for (int pt = 0; pt < 2; pt++) {
      int tloc = w * 2 + pt;
      int pl = tloc * 16 + lr;
      f32x4 a0 = {0,0,0,0}, a1 = {0,0,0,0}, a2 = {0,0,0,0};
      f32x4 a3 = {0,0,0,0}, a4 = {0,0,0,0}, a5 = {0,0,0,0};
#pragma unroll
      for (int ks = 0; ks < 3; ks++) {
        bf16x8 bf_ = *(const bf16x8*)&sT[pl * CROW + ks * 16 + kg * 4];
        a0 = __builtin_amdgcn_mfma_f32_16x16x32_bf16(wf_[0][ks], bf_, a0, 0, 0, 0);
        a1 = __builtin_amdgcn_mfma_f32_16x16x32_bf16(wf_[1][ks], bf_, a1, 0, 0, 0);
        a2 = __builtin_amdgcn_mfma_f32_16x16x32_bf16(wf_[2][ks], bf_, a2, 0, 0, 0);
        a3 = __builtin_amdgcn_mfma_f32_16x16x32_bf16(wf_[3][ks], bf_, a3, 0, 0, 0);
        a4 = __builtin_amdgcn_mfma_f32_16x16x32_bf16(wf_[4][ks], bf_, a4, 0, 0, 0);
        a5 = __builtin_amdgcn_mfma_f32_16x16x32_bf16(wf_[5][ks], bf_, a5, 0, 0, 0);
      }
      f32x4 accs[6] = {a0, a1, a2, a3, a4, a5};
      int px = rp0 + tloc * 16 + lr;
#pragma unroll
      for (int t = 0; t < 6; t++)
#pragma unroll
        for (int r = 0; r < 4; r++) {
          int oc = t * 16 + kg * 4 + r;
          float v = accs[t][r] * sc[t][r] + sh[t][r];
          v = v >= 0.f ? v : al * v;
          out[((size_t)(bo + oc) << 16) + px] = v;
        }
    }
  }
}

extern "C" void kernel_launch(void* const* d_in, const int* in_sizes, int n_in,
                              void* d_out, int out_size, void* d_ws, size_t ws_size,
                              hipStream_t stream) {
  const float* x   = (const float*)d_in[0];
  const float* w[3]  = {(const float*)d_in[1], (const float*)d_in[4], (const float*)d_in[7]};
  const float* bb[3] = {(const float*)d_in[2], (const float*)d_in[5], (const float*)d_in[8]};
  const float* aa[3] = {(const float*)d_in[3], (const float*)d_in[6], (const float*)d_in[9]};
  const float* wfp = (const float*)d_in[10];
  const float* bfv = (const float*)d_in[11];
  const float* af  = (const float*)d_in[12];
  float* out = (float*)d_out;

  // workspace layout (bytes):
  //   cat  bf16  201,326,592
  //   fraw bf16   67,108,864
  //   cur1 f32  786,432 el (aliased later by G2/musum/scale/shift/wbf)
  //   cur2 f32  196,608 el
  //   sacc f32  3,072 el ; wA3 bf16 3*5120
  char* ws = (char*)d_ws;
  bf16*  cat  = (bf16*)ws;
  bf16*  fraw = (bf16*)(ws + 201326592ull);
  float* cur1 = (float*)(ws + 201326592ull + 67108864ull);
  float* cur2 = cur1 + 786432;
  float* sacc = cur2 + 196608;
  bf16*  wA3  = (bf16*)(sacc + 3072);
  float* G2    = cur1;                  // alias (cur1 dead by then)
  float* musum = G2 + 16 * OC * OC;
  float* scale = musum + 16 * OC;
  float* shift = scale + 16 * OC;
  bf16*  wbf   = (bf16*)(shift + 16 * OC);

  auto cdiv = [](int a, int b) { return (a + b - 1) / b; };

  hipMemsetAsync(sacc, 0, 3072 * sizeof(float), stream);
  k_wprep3<<<60, 256, 0, stream>>>(w[0], w[1], w[2], wA3);

  k_avgpool<<<cdiv(B * CIN * 128 * 128, 256), 256, 0, stream>>>(x, cur1, 128, 128);
  k_avgpool<<<cdiv(B * CIN * 64 * 64, 256), 256, 0, stream>>>(cur1, cur2, 64, 64);

  const float* curp[3] = {x, cur1, cur2};
  int Hls[3] = {256, 128, 64};
  for (int l = 0; l < 3; l++) {
    int Hl = Hls[l];
    int ntx = Hl / 32;
    dim3 g3(ntx * ntx, B);
    k_fused3<<<g3, 256, 0, stream>>>(curp[l], wA3 + l * 5120, bb[l], fraw,
                                     sacc + l * 1024, Hl, ntx);
    if (l == 0)
      k_norm0<<<cdiv(B * OPL * H * W / 8, 256), 256, 0, stream>>>(fraw, sacc, aa[0], cat);
    else
      k_upnorm<<<cdiv(B * OPL * H * W / 2, 256), 256, 0, stream>>>(fraw, sacc + l * 1024,
          aa[l], cat, Hl, 256 / Hl, l * OPL, 1.f / (float)(Hl * Hl));
  }

  k_wprep<<<36, 256, 0, stream>>>(wfp, wbf);
  hipMemsetAsync(G2, 0, (size_t)(16 * OC * OC + 16 * OC) * sizeof(float), stream);
  k_moments<<<16 * 32, 384, 0, stream>>>(cat, G2, musum);
  dim3 gs(OC, B);
  k_statsF<<<gs, 128, 0, stream>>>(G2, musum, wfp, bfv, scale, shift);
  k_conv1x1f<<<16 * 64, 256, 0, stream>>>(cat, wbf, scale, shift, af, out);
}

// Round 6
// 661.946 us; speedup vs baseline: 2.0576x; 1.0144x over previous
//
#include <hip/hip_runtime.h>
#include <hip/hip_bf16.h>

typedef __hip_bfloat16 bf16;
typedef __attribute__((ext_vector_type(8))) short bf16x8;
typedef __attribute__((ext_vector_type(4))) float f32x4;
typedef __attribute__((ext_vector_type(2))) float f32x2;

constexpr int B = 16, CIN = 3, H = 256, W = 256;
constexpr int OPL = 32, WAVC = 12, OC = 96;
#define EPS 1e-5f

// fraw level offsets (elements): L0 = 16*32*65536, L1 = 16*32*16384, L2 = 16*32*4096
constexpr size_t FR_L1 = 33554432ull;
constexpr size_t FR_L2 = 41943040ull;
constexpr size_t FR_TOT = 44040192ull;   // elements (88,080,384 bytes)

// ---------------- prep: zero accumulators + convert/pack all weights ----------------
__global__ void k_prep(const float* __restrict__ w0, const float* __restrict__ w1,
                       const float* __restrict__ w2, const float* __restrict__ wf,
                       float* __restrict__ sacc, float* __restrict__ G2zone,
                       bf16* __restrict__ wA, bf16* __restrict__ wbf) {
  int i = blockIdx.x * 256 + threadIdx.x;
  if (i < 3072) sacc[i] = 0.f;
  if (i < 147456 + 1536) G2zone[i] = 0.f;          // G2 + musum
  if (i < OC * OC) wbf[i] = __float2bfloat16(wf[i]);
  if (i < 3 * 5120) {
    int l = i / 5120, rem = i % 5120;
    int entry = rem >> 5, kk = rem & 31;
    int r = entry >> 5, g = (entry >> 4) & 1, lr = entry & 15;
    int t2 = kk >> 4, ic = kk & 15;
    int tap = 2 * r + t2;
    const float* wl = l == 0 ? w0 : (l == 1 ? w1 : w2);
    float v = 0.f;
    if (tap <= 8 && ic < 12) v = wl[((g * 16 + lr) * 12 + ic) * 9 + tap];
    wA[i] = __float2bfloat16(v);
  }
}

// ---------------- avg pool 2x2, vectorized (2 out px / thread) ----------------
__global__ void k_avgpool2(const float* __restrict__ in, float* __restrict__ out,
                           int Ho, int Wo) {
  int n = B * CIN * Ho * Wo / 2;
  int t = blockIdx.x * blockDim.x + threadIdx.x;
  if (t >= n) return;
  int i = t * 2;
  int x2 = i % Wo, y = (i / Wo) % Ho, p = i / (Wo * Ho);
  int Wi = Wo * 2;
  const float* ip = in + (size_t)p * (Ho * 2) * Wi + (size_t)(2 * y) * Wi + 2 * x2;
  f32x4 r0 = *(const f32x4*)ip;
  f32x4 r1 = *(const f32x4*)(ip + Wi);
  f32x2 o;
  o[0] = 0.25f * (r0[0] + r0[1] + r1[0] + r1[1]);
  o[1] = 0.25f * (r0[2] + r0[3] + r1[2] + r1[3]);
  *(f32x2*)(out + i) = o;
}

// ---------------- FUSED: Haar bands + bilinear x2 up + conv3x3 (MFMA) + stats -------
// frawL is the per-level slice base.
__global__ void __launch_bounds__(256) k_fused3(const float* __restrict__ cur,
    const bf16* __restrict__ wA, const float* __restrict__ bias,
    bf16* __restrict__ frawL, float* __restrict__ sacc, int Hl, int ntx) {
  __shared__ unsigned int sPool[34 * 34 * 12 + 18 * 18 * 12];
  unsigned int* sInT = sPool;                         // [yy][xx][12]
  float* sCur = (float*)sPool;                        // [3][36][36]  (aliases sInT head)
  float* sBands = (float*)(sPool + 34 * 34 * 12);     // [ys][xs][3][4]

  int tile = blockIdx.x, b = blockIdx.y;
  int by = (tile / ntx) * 32, bx = (tile % ntx) * 32;
  int tid = threadIdx.x;
  int h2 = Hl >> 1;
  size_t plane = (size_t)Hl * Hl;

  int w = tid >> 6, l = tid & 63;
  int lr = l & 15, kg = l >> 4;
  int yloc = (w >> 1) * 16, xloc = (w & 1) * 16;
  bf16x8 wf_[5][2];
#pragma unroll
  for (int r = 0; r < 5; r++)
#pragma unroll
    for (int g = 0; g < 2; g++)
      wf_[r][g] = *(const bf16x8*)(wA + ((r * 2 + g) * 16 + lr) * 32 + kg * 8);
  int offr[5];
#pragma unroll
  for (int r = 0; r < 5; r++) {
    int tap = 2 * r + (kg >> 1);
    if (tap > 8) tap = 8;
    int dy = tap / 3 - 1, dx = tap - (tap / 3) * 3 - 1;
    offr[r] = (dy * 34 + dx) * 12 + (kg & 1) * 4;
  }
  float bi[2][4];
#pragma unroll
  for (int g = 0; g < 2; g++)
#pragma unroll
    for (int rg = 0; rg < 4; rg++)
      bi[g][rg] = bias[g * 16 + kg * 4 + rg];

  // --- phase A: load cur tile, clamped ---
  const float* cb = cur + (size_t)(b * CIN) * plane;
  for (int it = tid; it < 3 * 36 * 36; it += 256) {
    int xx = it % 36, rest = it / 36, yy = rest % 36, c = rest / 36;
    int gy = by - 2 + yy, gx = bx - 2 + xx;
    gy = gy < 0 ? 0 : (gy > Hl - 1 ? Hl - 1 : gy);
    gx = gx < 0 ? 0 : (gx > Hl - 1 ? Hl - 1 : gx);
    sCur[it] = cb[c * plane + (size_t)gy * Hl + gx];
  }
  __syncthreads();

  // --- phase B: Haar bands 18x18 ---
  for (int it = tid; it < 18 * 18 * 3; it += 256) {
    int c = it % 3, rest = it / 3, xs = rest % 18, ys = rest / 18;
    const float* cp = sCur + c * 1296 + (2 * ys) * 36 + 2 * xs;
    float e = cp[0], f = cp[1], g = cp[36], h = cp[37];
    f32x4 v;
    v[0] = (e + f + g + h) * 0.5f;
    v[1] = (e + f - g - h) * 0.5f;
    v[2] = (e - f + g - h) * 0.5f;
    v[3] = (e - f - g + h) * 0.5f;
    *(f32x4*)&sBands[(ys * 18 + xs) * 12 + c * 4] = v;
  }
  __syncthreads();

  // --- phase C: bilinear x2 expand into packed sInT ---
  int yb_base = (by >> 1) - 1, xb_base = (bx >> 1) - 1;
  for (int it = tid; it < 34 * 34 * 3; it += 256) {
    int c = it % 3, rest = it / 3, xx = rest % 34, yy = rest / 34;
    int base = (yy * 34 + xx) * 12 + c * 2;
    int Y = by - 1 + yy, X = bx - 1 + xx;
    if (Y < 0 || Y >= Hl || X < 0 || X >= Hl) {
      sInT[base] = 0; sInT[base + 1] = 0;
      continue;
    }
    int my = Y >> 1, dy = Y & 1;
    int y0 = my - 1 + dy;
    float wy = dy ? 0.25f : 0.75f;
    int y0c = y0 < 0 ? 0 : y0, y1c = (y0 + 1 > h2 - 1) ? h2 - 1 : y0 + 1;
    int ys0 = y0c - yb_base, ys1 = y1c - yb_base;
    int mx = X >> 1, dx = X & 1;
    int x0 = mx - 1 + dx;
    float wx = dx ? 0.25f : 0.75f;
    int x0c = x0 < 0 ? 0 : x0, x1c = (x0 + 1 > h2 - 1) ? h2 - 1 : x0 + 1;
    int xs0 = x0c - xb_base, xs1 = x1c - xb_base;
    f32x4 c00 = *(const f32x4*)&sBands[(ys0 * 18 + xs0) * 12 + c * 4];
    f32x4 c01 = *(const f32x4*)&sBands[(ys0 * 18 + xs1) * 12 + c * 4];
    f32x4 c10 = *(const f32x4*)&sBands[(ys1 * 18 + xs0) * 12 + c * 4];
    f32x4 c11 = *(const f32x4*)&sBands[(ys1 * 18 + xs1) * 12 + c * 4];
    f32x4 v0 = c00 + wx * (c01 - c00);
    f32x4 v1 = c10 + wx * (c11 - c10);
    f32x4 v = v0 + wy * (v1 - v0);
    unsigned int d0 = (unsigned int)__bfloat16_as_ushort(__float2bfloat16(v[0]))
                    | ((unsigned int)__bfloat16_as_ushort(__float2bfloat16(v[1])) << 16);
    unsigned int d1 = (unsigned int)__bfloat16_as_ushort(__float2bfloat16(v[2]))
                    | ((unsigned int)__bfloat16_as_ushort(__float2bfloat16(v[3])) << 16);
    sInT[base] = d0;
    sInT[base + 1] = d1;
  }
  for (int it = tid; it < 34 * 34; it += 256) {
    sInT[it * 12 + 6] = 0;
    sInT[it * 12 + 7] = 0;
  }
  __syncthreads();

  // --- MFMA conv + bf16 store + fused stats ---
  float s_[2][4], s2_[2][4];
#pragma unroll
  for (int g = 0; g < 2; g++)
#pragma unroll
    for (int rg = 0; rg < 4; rg++) { s_[g][rg] = 0.f; s2_[g][rg] = 0.f; }

  bf16* frb = frawL + (size_t)b * OPL * plane;
  for (int y = 0; y < 16; y++) {
    int rowbase = ((yloc + y + 1) * 34 + (xloc + lr + 1)) * 12;
    f32x4 a0 = {0, 0, 0, 0}, a1 = {0, 0, 0, 0};
#pragma unroll
    for (int r = 0; r < 5; r++) {
      bf16x8 bf_ = *(const bf16x8*)&sInT[rowbase + offr[r]];
      a0 = __builtin_amdgcn_mfma_f32_16x16x32_bf16(wf_[r][0], bf_, a0, 0, 0, 0);
      a1 = __builtin_amdgcn_mfma_f32_16x16x32_bf16(wf_[r][1], bf_, a1, 0, 0, 0);
    }
    int gy = by + yloc + y, gxp = bx + xloc + lr;
    size_t po = (size_t)gy * Hl + gxp;
#pragma unroll
    for (int rg = 0; rg < 4; rg++) {
      bf16 vb0 = __float2bfloat16(a0[rg] + bi[0][rg]);
      bf16 vb1 = __float2bfloat16(a1[rg] + bi[1][rg]);
      frb[(size_t)(kg * 4 + rg) * plane + po] = vb0;
      frb[(size_t)(16 + kg * 4 + rg) * plane + po] = vb1;
      float v0 = __bfloat162float(vb0), v1 = __bfloat162float(vb1);
      s_[0][rg] += v0; s2_[0][rg] += v0 * v0;
      s_[1][rg] += v1; s2_[1][rg] += v1 * v1;
    }
  }
#pragma unroll
  for (int g = 0; g < 2; g++)
#pragma unroll
    for (int rg = 0; rg < 4; rg++) {
      float s = s_[g][rg], s2 = s2_[g][rg];
#pragma unroll
      for (int m = 8; m >= 1; m >>= 1) {
        s += __shfl_xor(s, m);
        s2 += __shfl_xor(s2, m);
      }
      if (lr == 0) {
        int pc = b * OPL + g * 16 + kg * 4 + rg;
        atomicAdd(&sacc[pc * 2], s);
        atomicAdd(&sacc[pc * 2 + 1], s2);
      }
    }
}

// ---------------- all levels: normalize + prelu (+ bilinear up) -> cat, 8 px/thread -
__global__ void __launch_bounds__(256) k_normcat(const bf16* __restrict__ fraw,
    const float* __restrict__ sacc, const float* __restrict__ a0,
    const float* __restrict__ a1, const float* __restrict__ a2,
    bf16* __restrict__ cat) {
  int t = blockIdx.x * 256 + threadIdx.x;
  if (t >= B * OC * H * W / 8) return;
  int pc96 = t >> 13;               // 8192 threads per 256^2 plane
  int b = pc96 / OC, c = pc96 - b * OC;
  int tloc = t & 8191;
  bf16x8 o;
  if (c < 32) {
    int pcl = b * 32 + c;
    const float invN = 1.f / 65536.f;
    float mean = sacc[pcl * 2] * invN;
    float var = sacc[pcl * 2 + 1] * invN - mean * mean;
    float rstd = rsqrtf(fmaxf(var, 0.f) + EPS);
    float al = a0[0];
    bf16x8 in = *(const bf16x8*)(fraw + (((size_t)pcl) << 16) + tloc * 8);
#pragma unroll
    for (int j = 0; j < 8; j++) {
      float v = __bfloat162float(__ushort_as_bfloat16((unsigned short)in[j]));
      v = (v - mean) * rstd;
      v = v >= 0.f ? v : al * v;
      o[j] = (short)__bfloat16_as_ushort(__float2bfloat16(v));
    }
  } else {
    int lvl = c < 64 ? 1 : 2;
    int cl = c - 32 * lvl;
    int pcl = b * 32 + cl;
    int n = (lvl == 1) ? 128 : 64;
    int shift = (lvl == 1) ? 14 : 12;
    size_t lvloff = (lvl == 1) ? FR_L1 : FR_L2;
    const float* sl = sacc + lvl * 1024;
    float invN = 1.f / (float)(n * n);
    float mean = sl[pcl * 2] * invN;
    float var = sl[pcl * 2 + 1] * invN - mean * mean;
    float rstd = rsqrtf(fmaxf(var, 0.f) + EPS);
    float al = (lvl == 1) ? a1[0] : a2[0];
    const bf16* ip = fraw + lvloff + (((size_t)pcl) << shift);
    int X0 = (tloc & 31) * 8, y = tloc >> 5;
    int y0; float wy;
    if (lvl == 1) { int d = y & 1; y0 = (y >> 1) - 1 + d; wy = d ? 0.25f : 0.75f; }
    else {
      int d = y & 3; y0 = (y >> 2) - 1 + (d >> 1);
      wy = (d & 1) ? ((d >> 1) ? 0.375f : 0.875f) : ((d >> 1) ? 0.125f : 0.625f);
    }
    int y0c = y0 < 0 ? 0 : y0;
    int y1c = (y0 + 1 > n - 1) ? n - 1 : y0 + 1;
    const bf16* r0p = ip + (size_t)y0c * n;
    const bf16* r1p = ip + (size_t)y1c * n;
#pragma unroll
    for (int j = 0; j < 8; j++) {
      int x = X0 + j;
      int x0; float wx;
      if (lvl == 1) { int d = x & 1; x0 = (x >> 1) - 1 + d; wx = d ? 0.25f : 0.75f; }
      else {
        int d = x & 3; x0 = (x >> 2) - 1 + (d >> 1);
        wx = (d & 1) ? ((d >> 1) ? 0.375f : 0.875f) : ((d >> 1) ? 0.125f : 0.625f);
      }
      int x0c = x0 < 0 ? 0 : x0;
      int x1c = (x0 + 1 > n - 1) ? n - 1 : x0 + 1;
      float v00 = __bfloat162float(r0p[x0c]);
      float v01 = __bfloat162float(r0p[x1c]);
      float v10 = __bfloat162float(r1p[x0c]);
      float v11 = __bfloat162float(r1p[x1c]);
      v00 = (v00 - mean) * rstd; v00 = v00 >= 0.f ? v00 : al * v00;
      v01 = (v01 - mean) * rstd; v01 = v01 >= 0.f ? v01 : al * v01;
      v10 = (v10 - mean) * rstd; v10 = v10 >= 0.f ? v10 : al * v10;
      v11 = (v11 - mean) * rstd; v11 = v11 >= 0.f ? v11 : al * v11;
      float v = (1.f - wy) * ((1.f - wx) * v00 + wx * v01)
              + wy * ((1.f - wx) * v10 + wx * v11);
      o[j] = (short)__bfloat16_as_ushort(__float2bfloat16(v));
    }
  }
  *(bf16x8*)(cat + (((size_t)pc96) << 16) + tloc * 8) = o;
}

// ---------------- second moments of cat per batch: G2 = cat*cat^T, musum ----------------
__global__ void __launch_bounds__(384) k_moments(const bf16* __restrict__ cat,
    float* __restrict__ G2, float* __restrict__ musum) {
  int b = blockIdx.x >> 5;
  int chunk = blockIdx.x & 31;
  int ti = threadIdx.x >> 6;
  int l = threadIdx.x & 63;
  int lr = l & 15, kg = l >> 4;
  const bf16* base = cat + ((size_t)(b * OC) << 16);
  f32x4 acc0 = {0,0,0,0}, acc1 = {0,0,0,0}, acc2 = {0,0,0,0};
  f32x4 acc3 = {0,0,0,0}, acc4 = {0,0,0,0}, acc5 = {0,0,0,0};
  f32x4 accO = {0,0,0,0};
  bf16x8 ones;
#pragma unroll
  for (int j = 0; j < 8; j++) ones[j] = (short)0x3F80;
  int p0 = chunk * 2048 + kg * 8;
  const bf16* arow = base + (((size_t)(ti * 16 + lr)) << 16);
#pragma unroll 2
  for (int s = 0; s < 64; s++) {
    int p = p0 + s * 32;
    bf16x8 fa = *(const bf16x8*)(arow + p);
    bf16x8 f0 = *(const bf16x8*)(base + (((size_t)(0 + lr)) << 16) + p);
    bf16x8 f1 = *(const bf16x8*)(base + (((size_t)(16 + lr)) << 16) + p);
    bf16x8 f2 = *(const bf16x8*)(base + (((size_t)(32 + lr)) << 16) + p);
    bf16x8 f3 = *(const bf16x8*)(base + (((size_t)(48 + lr)) << 16) + p);
    bf16x8 f4 = *(const bf16x8*)(base + (((size_t)(64 + lr)) << 16) + p);
    bf16x8 f5 = *(const bf16x8*)(base + (((size_t)(80 + lr)) << 16) + p);
    acc0 = __builtin_amdgcn_mfma_f32_16x16x32_bf16(fa, f0, acc0, 0, 0, 0);
    acc1 = __builtin_amdgcn_mfma_f32_16x16x32_bf16(fa, f1, acc1, 0, 0, 0);
    acc2 = __builtin_amdgcn_mfma_f32_16x16x32_bf16(fa, f2, acc2, 0, 0, 0);
    acc3 = __builtin_amdgcn_mfma_f32_16x16x32_bf16(fa, f3, acc3, 0, 0, 0);
    acc4 = __builtin_amdgcn_mfma_f32_16x16x32_bf16(fa, f4, acc4, 0, 0, 0);
    acc5 = __builtin_amdgcn_mfma_f32_16x16x32_bf16(fa, f5, acc5, 0, 0, 0);
    accO = __builtin_amdgcn_mfma_f32_16x16x32_bf16(fa, ones, accO, 0, 0, 0);
  }
  f32x4 accs[6] = {acc0, acc1, acc2, acc3, acc4, acc5};
#pragma unroll
  for (int t = 0; t < 6; t++)
#pragma unroll
    for (int r = 0; r < 4; r++) {
      int i = ti * 16 + kg * 4 + r, j = t * 16 + lr;
      atomicAdd(&G2[(size_t)(b * OC + i) * OC + j], accs[t][r]);
    }
#pragma unroll
  for (int r = 0; r < 4; r++) {
    int i = ti * 16 + kg * 4 + r;
    if (lr == 0) atomicAdd(&musum[b * OC + i], accO[r]);
  }
}

// ---------------- combine: per (b,oc) scale/shift for fused IN ----------------
__global__ void __launch_bounds__(128) k_statsF(const float* __restrict__ G2,
    const float* __restrict__ musum, const float* __restrict__ wf,
    const float* __restrict__ bfv, float* __restrict__ scale,
    float* __restrict__ shift) {
  int oc = blockIdx.x, b = blockIdx.y;
  int j = threadIdx.x;
  float quad = 0.f, lin = 0.f;
  if (j < OC) {
    float wj = __bfloat162float(__float2bfloat16(wf[oc * OC + j]));
    const float* g = G2 + (size_t)(b * OC) * OC + j;
    float inner = 0.f;
#pragma unroll 4
    for (int i = 0; i < OC; i++) {
      float wi = __bfloat162float(__float2bfloat16(wf[oc * OC + i]));
      inner = fmaf(wi, g[(size_t)i * OC], inner);
    }
    quad = wj * inner;
    lin = wj * musum[b * OC + j];
  }
  __shared__ float rq[2], rl[2];
  for (int off = 32; off > 0; off >>= 1) {
    quad += __shfl_down(quad, off);
    lin += __shfl_down(lin, off);
  }
  if ((threadIdx.x & 63) == 0) { rq[threadIdx.x >> 6] = quad; rl[threadIdx.x >> 6] = lin; }
  __syncthreads();
  if (threadIdx.x == 0) {
    float Q = rq[0] + rq[1], L = rl[0] + rl[1];
    const float invN = 1.f / 65536.f;
    float bias = bfv[oc];
    float mean = L * invN + bias;
    float e2 = Q * invN + 2.f * bias * (L * invN) + bias * bias;
    float var = e2 - mean * mean;
    float rstd = rsqrtf(fmaxf(var, 0.f) + EPS);
    scale[b * OC + oc] = rstd;
    shift[b * OC + oc] = (bias - mean) * rstd;
  }
}

// ---------------- fused final conv1x1 (MFMA) + IN + prelu -> d_out ------------------
constexpr int CROW = 52;
__global__ void __launch_bounds__(256) k_conv1x1f(const bf16* __restrict__ cat,
    const bf16* __restrict__ wbf, const float* __restrict__ scale,
    const float* __restrict__ shift, const float* __restrict__ af,
    float* __restrict__ out) {
  __shared__ unsigned int sT[128 * CROW];
  int b = blockIdx.x >> 6;
  int px0 = (blockIdx.x & 63) * 1024;
  int tid = threadIdx.x, w = tid >> 6, l = tid & 63;
  int lr = l & 15, kg = l >> 4;
  bf16x8 wf_[6][3];
#pragma unroll
  for (int t = 0; t < 6; t++)
#pragma unroll
    for (int ks = 0; ks < 3; ks++)
      wf_[t][ks] = *(const bf16x8*)(wbf + (t * 16 + lr) * OC + ks * 32 + kg * 8);
  float al = af[0];
  int bo = b * OC;
  const f32x4* scv = (const f32x4*)(scale + bo);
  const f32x4* shv = (const f32x4*)(shift + bo);
  const bf16* cb = cat + ((size_t)bo << 16);

  bf16x8 pa[3], pc_[3];
#define LOADR(RP0)                                                         \
  {                                                                        \
    _Pragma("unroll")                                                      \
    for (int k = 0; k < 3; k++) {                                          \
      int it = tid + k * 256;                                              \
      int p = it % 48, g = it / 48;                                        \
      const bf16* r0 = cb + (((size_t)(2 * p)) << 16) + (RP0) + g * 8;     \
      pa[k] = *(const bf16x8*)r0;                                          \
      pc_[k] = *(const bf16x8*)(r0 + 65536);                               \
    }                                                                      \
  }
  LOADR(px0);
  for (int round = 0; round < 8; round++) {
    int rp0 = px0 + round * 128;
    __syncthreads();
#pragma unroll
    for (int k = 0; k < 3; k++) {
      int it = tid + k * 256;
      int p = it % 48, g = it / 48;
#pragma unroll
      for (int j = 0; j < 8; j++) {
        unsigned int d = (unsigned int)(unsigned short)pa[k][j]
                       | ((unsigned int)(unsigned short)pc_[k][j] << 16);
        sT[(g * 8 + j) * CROW + p] = d;
      }
    }
    __syncthreads();
    if (round < 7) LOADR(px0 + (round + 1) * 128);
#pragma unroll
    for (int pt = 0; pt < 2; pt++) {
      int tloc = w * 2 + pt;
      int pl = tloc * 16 + lr;
      f32x4 a0 = {0,0,0,0}, a1 = {0,0,0,0}, a2 = {0,0,0,0};
      f32x4 a3 = {0,0,0,0}, a4 = {0,0,0,0}, a5 = {0,0,0,0};
#pragma unroll
      for (int ks = 0; ks < 3; ks++) {
        bf16x8 bf_ = *(const bf16x8*)&sT[pl * CROW + ks * 16 + kg * 4];
        a0 = __builtin_amdgcn_mfma_f32_16x16x32_bf16(wf_[0][ks], bf_, a0, 0, 0, 0);
        a1 = __builtin_amdgcn_mfma_f32_16x16x32_bf16(wf_[1][ks], bf_, a1, 0, 0, 0);
        a2 = __builtin_amdgcn_mfma_f32_16x16x32_bf16(wf_[2][ks], bf_, a2, 0, 0, 0);
        a3 = __builtin_amdgcn_mfma_f32_16x16x32_bf16(wf_[3][ks], bf_, a3, 0, 0, 0);
        a4 = __builtin_amdgcn_mfma_f32_16x16x32_bf16(wf_[4][ks], bf_, a4, 0, 0, 0);
        a5 = __builtin_amdgcn_mfma_f32_16x16x32_bf16(wf_[5][ks], bf_, a5, 0, 0, 0);
      }
      f32x4 accs[6] = {a0, a1, a2, a3, a4, a5};
      int px = rp0 + tloc * 16 + lr;
#pragma unroll
      for (int t = 0; t < 6; t++) {
        f32x4 sc4 = scv[t * 4 + kg];
        f32x4 sh4 = shv[t * 4 + kg];
#pragma unroll
        for (int r = 0; r < 4; r++) {
          int oc = t * 16 + kg * 4 + r;
          float v = accs[t][r] * sc4[r] + sh4[r];
          v = v >= 0.f ? v : al * v;
          out[((size_t)(bo + oc) << 16) + px] = v;
        }
      }
    }
  }
#undef LOADR
}

extern "C" void kernel_launch(void* const* d_in, const int* in_sizes, int n_in,
                              void* d_out, int out_size, void* d_ws, size_t ws_size,
                              hipStream_t stream) {
  const float* x   = (const float*)d_in[0];
  const float* w[3]  = {(const float*)d_in[1], (const float*)d_in[4], (const float*)d_in[7]};
  const float* bb[3] = {(const float*)d_in[2], (const float*)d_in[5], (const float*)d_in[8]};
  const float* aa[3] = {(const float*)d_in[3], (const float*)d_in[6], (const float*)d_in[9]};
  const float* wfp = (const float*)d_in[10];
  const float* bfv = (const float*)d_in[11];
  const float* af  = (const float*)d_in[12];
  float* out = (float*)d_out;

  // workspace layout:
  //   cat  bf16  201,326,592 B
  //   fraw bf16   88,080,384 B  (all 3 levels disjoint: L0 | L1 | L2)
  //   cur1 f32   786,432 el; cur2 f32 196,608 el
  //   sacc f32   3,072 el; wA3 bf16 15,360
  //   G2 f32 147,456; musum/scale/shift f32 1,536 each; wbf bf16 9,216
  char* ws = (char*)d_ws;
  bf16*  cat  = (bf16*)ws;
  bf16*  fraw = (bf16*)(ws + 201326592ull);
  float* cur1 = (float*)(ws + 201326592ull + FR_TOT * 2ull);
  float* cur2 = cur1 + 786432;
  float* sacc = cur2 + 196608;
  bf16*  wA3  = (bf16*)(sacc + 3072);
  float* G2   = (float*)(wA3 + 15360);
  float* musum = G2 + 147456;
  float* scale = musum + 1536;
  float* shift = scale + 1536;
  bf16*  wbf   = (bf16*)(shift + 1536);

  auto cdiv = [](int a, int b) { return (a + b - 1) / b; };

  k_prep<<<582, 256, 0, stream>>>(w[0], w[1], w[2], wfp, sacc, G2, wA3, wbf);

  k_avgpool2<<<cdiv(B * CIN * 128 * 128 / 2, 256), 256, 0, stream>>>(x, cur1, 128, 128);
  k_avgpool2<<<cdiv(B * CIN * 64 * 64 / 2, 256), 256, 0, stream>>>(cur1, cur2, 64, 64);

  const float* curp[3] = {x, cur1, cur2};
  bf16* frawL[3] = {fraw, fraw + FR_L1, fraw + FR_L2};
  int Hls[3] = {256, 128, 64};
  for (int l = 0; l < 3; l++) {
    int Hl = Hls[l];
    int ntx = Hl / 32;
    dim3 g3(ntx * ntx, B);
    k_fused3<<<g3, 256, 0, stream>>>(curp[l], wA3 + l * 5120, bb[l], frawL[l],
                                     sacc + l * 1024, Hl, ntx);
  }
  k_normcat<<<cdiv(B * OC * H * W / 8, 256), 256, 0, stream>>>(fraw, sacc, aa[0],
                                                               aa[1], aa[2], cat);
  k_moments<<<16 * 32, 384, 0, stream>>>(cat, G2, musum);
  dim3 gs(OC, B);
  k_statsF<<<gs, 128, 0, stream>>>(G2, musum, wfp, bfv, scale, shift);
  k_conv1x1f<<<16 * 64, 256, 0, stream>>>(cat, wbf, scale, shift, af, out);
}